// Round 1
// baseline (519.795 us; speedup 1.0000x reference)
//
#include <hip/hip_runtime.h>

typedef __attribute__((ext_vector_type(4))) float f32x4;
typedef __attribute__((ext_vector_type(8))) _Float16 f16x8;
typedef __attribute__((ext_vector_type(4))) _Float16 f16x4;

#define SEQ 2048
#define DM 2048
#define NQKV 6144

// ---------------- elementwise convert f32 -> f16 (vectorized) ----------------
__global__ __launch_bounds__(256) void cvt_x_kernel(const float* __restrict__ X,
                                                    _Float16* __restrict__ Xb, int n4) {
  int i = blockIdx.x * 256 + threadIdx.x;
  if (i < n4) {
    const float4 v = ((const float4*)X)[i];
    f16x4 o;
    o.x = (_Float16)v.x; o.y = (_Float16)v.y; o.z = (_Float16)v.z; o.w = (_Float16)v.w;
    ((f16x4*)Xb)[i] = o;
  }
}

// ---------------- tiled transpose + convert: W[K][N] f32 -> Wt[N][K] f16 -----
__global__ __launch_bounds__(256) void wtrans_kernel(const float* __restrict__ W,
                                                     _Float16* __restrict__ Wt,
                                                     int K, int N) {
  __shared__ float tile[32][33];
  const int n0 = blockIdx.x * 32, k0 = blockIdx.y * 32;
  const int tx = threadIdx.x & 31, ty = threadIdx.x >> 5;  // 32 x 8
#pragma unroll
  for (int i = 0; i < 32; i += 8)
    tile[ty + i][tx] = W[(size_t)(k0 + ty + i) * N + n0 + tx];
  __syncthreads();
#pragma unroll
  for (int i = 0; i < 32; i += 8)
    Wt[(size_t)(n0 + ty + i) * K + k0 + tx] = (_Float16)tile[tx][ty + i];
}

// ---------------- RoPE cos/sin table: [2048 pos][64 freq] --------------------
__global__ __launch_bounds__(256) void rope_table_kernel(float* __restrict__ ct,
                                                         float* __restrict__ st) {
  int i = blockIdx.x * 256 + threadIdx.x;  // 131072
  int pos = i >> 6, f = i & 63;
  float inv = powf(10000.0f, -(float)f / 64.0f);
  float ang = (float)pos * inv;
  ct[i] = cosf(ang);
  st[i] = sinf(ang);
}

// ---------------- GEMM: A[M][K] f16 (row-major) x Bt[N][K] f16 ---------------
// 128x128 tile, BK=64, 4 waves (2x2), each wave 64x64 via 4x4 of 16x16x32 MFMA.
template <bool OUTF32>
__global__ __launch_bounds__(256) void gemm_f16_kernel(const _Float16* __restrict__ A,
                                                       const _Float16* __restrict__ Bt,
                                                       void* __restrict__ Cout,
                                                       int M, int N, int K) {
  __shared__ __align__(16) _Float16 As[128][72];
  __shared__ __align__(16) _Float16 Bs[128][72];
  const int bm = blockIdx.y * 128, bn = blockIdx.x * 128;
  const int t = threadIdx.x, lane = t & 63, w = t >> 6;
  const int wm = w >> 1, wn = w & 1;
  f32x4 acc[4][4];
#pragma unroll
  for (int i = 0; i < 4; ++i)
#pragma unroll
    for (int j = 0; j < 4; ++j) acc[i][j] = (f32x4)0.0f;

  for (int kt = 0; kt < K; kt += 64) {
#pragma unroll
    for (int i = 0; i < 4; ++i) {
      int c = i * 256 + t;          // 1024 chunks of 8 f16
      int row = c >> 3, kc = (c & 7) * 8;
      *(f16x8*)&As[row][kc] = *(const f16x8*)&A[(size_t)(bm + row) * K + kt + kc];
      *(f16x8*)&Bs[row][kc] = *(const f16x8*)&Bt[(size_t)(bn + row) * K + kt + kc];
    }
    __syncthreads();
#pragma unroll
    for (int kk = 0; kk < 2; ++kk) {
      const int ko = kk * 32 + (lane >> 4) * 8, rr = lane & 15;
      f16x8 af[4], bf[4];
#pragma unroll
      for (int i = 0; i < 4; ++i) af[i] = *(const f16x8*)&As[wm * 64 + i * 16 + rr][ko];
#pragma unroll
      for (int j = 0; j < 4; ++j) bf[j] = *(const f16x8*)&Bs[wn * 64 + j * 16 + rr][ko];
#pragma unroll
      for (int i = 0; i < 4; ++i)
#pragma unroll
        for (int j = 0; j < 4; ++j)
          acc[i][j] = __builtin_amdgcn_mfma_f32_16x16x32_f16(af[i], bf[j], acc[i][j], 0, 0, 0);
    }
    __syncthreads();
  }
  const int cr = (lane >> 4) * 4, cc = lane & 15;
#pragma unroll
  for (int i = 0; i < 4; ++i)
#pragma unroll
    for (int j = 0; j < 4; ++j) {
      int col = bn + wn * 64 + j * 16 + cc;
#pragma unroll
      for (int r = 0; r < 4; ++r) {
        int row = bm + wm * 64 + i * 16 + cr + r;
        if (OUTF32)
          ((float*)Cout)[(size_t)row * N + col] = acc[i][j][r];
        else
          ((_Float16*)Cout)[(size_t)row * N + col] = (_Float16)acc[i][j][r];
      }
    }
}

// ---------------- RoPE on Q,K (from QKV gemm out), scale folded into Q -------
__global__ __launch_bounds__(256) void rope_qk_kernel(const _Float16* __restrict__ QKVo,
                                                      const int* __restrict__ pos_ids,
                                                      const float* __restrict__ ct,
                                                      const float* __restrict__ st,
                                                      _Float16* __restrict__ Q,
                                                      _Float16* __restrict__ K) {
  int id = blockIdx.x * 256 + threadIdx.x;  // 2^22 = B*S*H*64
  int f = id & 63;
  int h = (id >> 6) & 15;
  int s_ = (id >> 10) & 2047;
  int b = (id >> 21) & 1;
  int row = b * SEQ + s_;
  int pos = pos_ids[row];
  float c = ct[pos * 64 + f], sn = st[pos * 64 + f];
  size_t base = (size_t)row * NQKV;
  float q1 = (float)QKVo[base + h * 128 + f];
  float q2 = (float)QKVo[base + h * 128 + f + 64];
  float k1 = (float)QKVo[base + 2048 + h * 128 + f];
  float k2 = (float)QKVo[base + 2048 + h * 128 + f + 64];
  const float scale = 0.08838834764831845f;  // 1/sqrt(128)
  size_t obase = (((size_t)(b * 16 + h)) * SEQ + s_) * 128;
  Q[obase + f]      = (_Float16)((q1 * c - q2 * sn) * scale);
  Q[obase + f + 64] = (_Float16)((q2 * c + q1 * sn) * scale);
  K[obase + f]      = (_Float16)(k1 * c - k2 * sn);
  K[obase + f + 64] = (_Float16)(k2 * c + k1 * sn);
}

// ---------------- V transpose: QKVo v-part -> Vt[bh][128][S] -----------------
__global__ __launch_bounds__(256) void v_transpose_kernel(const _Float16* __restrict__ QKVo,
                                                          _Float16* __restrict__ Vt) {
  __shared__ _Float16 tile[32][40];
  const int s0 = blockIdx.x * 32, d0 = blockIdx.y * 32, bh = blockIdx.z;
  const int b = bh >> 4, h = bh & 15;
  const int tx = threadIdx.x & 31, ty = threadIdx.x >> 5;
#pragma unroll
  for (int i = 0; i < 32; i += 8) {
    int s_ = s0 + ty + i;
    tile[ty + i][tx] = QKVo[(size_t)(b * SEQ + s_) * NQKV + 4096 + h * 128 + d0 + tx];
  }
  __syncthreads();
#pragma unroll
  for (int i = 0; i < 32; i += 8) {
    int d = d0 + ty + i;
    Vt[((size_t)bh * 128 + d) * SEQ + s0 + tx] = tile[tx][ty + i];
  }
}

// ---------------- flash attention, causal ------------------------------------
// block = 64 q-rows of one (b,h); 4 waves x 16 rows; K-tiles of 64.
__global__ __launch_bounds__(256) void attn_kernel(const _Float16* __restrict__ Q,
                                                   const _Float16* __restrict__ K,
                                                   const _Float16* __restrict__ Vt,
                                                   _Float16* __restrict__ O) {
  __shared__ __align__(16) _Float16 Ks[64][136];
  __shared__ __align__(16) _Float16 Vs[128][72];
  __shared__ __align__(16) _Float16 Ps[4][16][72];
  const int q0 = blockIdx.x * 64;
  const int bh = blockIdx.y;
  const int b = bh >> 4, h = bh & 15;
  const int t = threadIdx.x, lane = t & 63, w = t >> 6;
  const int lr = lane >> 4, lc = lane & 15;
  const _Float16* Qb = Q + (size_t)bh * SEQ * 128;
  const _Float16* Kb = K + (size_t)bh * SEQ * 128;
  const _Float16* Vb = Vt + (size_t)bh * 128 * SEQ;

  f16x8 qf[4];
  {
    int qrow = q0 + w * 16 + lc;
#pragma unroll
    for (int kk = 0; kk < 4; ++kk)
      qf[kk] = *(const f16x8*)&Qb[(size_t)qrow * 128 + kk * 32 + lr * 8];
  }
  f32x4 acco[8];
#pragma unroll
  for (int i = 0; i < 8; ++i) acco[i] = (f32x4)0.0f;
  float m_r[4] = {-1e30f, -1e30f, -1e30f, -1e30f};
  float l_r[4] = {0.f, 0.f, 0.f, 0.f};

  const int nkb = q0 / 64 + 1;
  for (int kb = 0; kb < nkb; ++kb) {
    const int k0 = kb * 64;
    // stage K [64][128] and Vt [128][64]
#pragma unroll
    for (int i = 0; i < 4; ++i) {
      int c = i * 256 + t;
      {
        int row = c >> 4, kc = (c & 15) * 8;
        *(f16x8*)&Ks[row][kc] = *(const f16x8*)&Kb[(size_t)(k0 + row) * 128 + kc];
      }
      {
        int row = c >> 3, kc = (c & 7) * 8;
        *(f16x8*)&Vs[row][kc] = *(const f16x8*)&Vb[(size_t)row * SEQ + k0 + kc];
      }
    }
    __syncthreads();

    // S = Q K^T  (per wave: 16 q-rows x 64 keys)
    f32x4 sacc[4];
#pragma unroll
    for (int j = 0; j < 4; ++j) sacc[j] = (f32x4)0.0f;
#pragma unroll
    for (int j = 0; j < 4; ++j)
#pragma unroll
      for (int kk = 0; kk < 4; ++kk) {
        f16x8 kf = *(const f16x8*)&Ks[j * 16 + lc][kk * 32 + lr * 8];
        sacc[j] = __builtin_amdgcn_mfma_f32_16x16x32_f16(qf[kk], kf, sacc[j], 0, 0, 0);
      }

    const bool diag = (k0 == q0);
#pragma unroll
    for (int r = 0; r < 4; ++r) {
      const int rowi = q0 + w * 16 + lr * 4 + r;
      float s[4], mx = -1e30f;
#pragma unroll
      for (int j = 0; j < 4; ++j) {
        float sv = sacc[j][r];
        if (diag && (k0 + j * 16 + lc > rowi)) sv = -1e30f;
        s[j] = sv;
        mx = fmaxf(mx, sv);
      }
#pragma unroll
      for (int msk = 1; msk < 16; msk <<= 1) mx = fmaxf(mx, __shfl_xor(mx, msk));
      const float mn = fmaxf(m_r[r], mx);
      const float sc = __expf(m_r[r] - mn);
      float rs = 0.f;
#pragma unroll
      for (int j = 0; j < 4; ++j) {
        float pv = __expf(s[j] - mn);
        rs += pv;
        Ps[w][lr * 4 + r][j * 16 + lc] = (_Float16)pv;
      }
#pragma unroll
      for (int msk = 1; msk < 16; msk <<= 1) rs += __shfl_xor(rs, msk);
      l_r[r] = l_r[r] * sc + rs;
      m_r[r] = mn;
#pragma unroll
      for (int tt = 0; tt < 8; ++tt) acco[tt][r] *= sc;
    }
    __syncthreads();

    // O += P V   (P: 16x64, V: 64x128)
#pragma unroll
    for (int tt = 0; tt < 8; ++tt)
#pragma unroll
      for (int ch = 0; ch < 2; ++ch) {
        f16x8 pf = *(const f16x8*)&Ps[w][lc][ch * 32 + lr * 8];
        f16x8 vf = *(const f16x8*)&Vs[tt * 16 + lc][ch * 32 + lr * 8];
        acco[tt] = __builtin_amdgcn_mfma_f32_16x16x32_f16(pf, vf, acco[tt], 0, 0, 0);
      }
    __syncthreads();
  }

  // epilogue: O[b*S+row][h*128+col] = acco / l
#pragma unroll
  for (int tt = 0; tt < 8; ++tt) {
    const int col = h * 128 + tt * 16 + lc;
#pragma unroll
    for (int r = 0; r < 4; ++r) {
      const int row = q0 + w * 16 + lr * 4 + r;
      O[(size_t)(b * SEQ + row) * DM + col] = (_Float16)(acco[tt][r] / l_r[r]);
    }
  }
}

// ---------------- launch ------------------------------------------------------
extern "C" void kernel_launch(void* const* d_in, const int* in_sizes, int n_in,
                              void* d_out, int out_size, void* d_ws, size_t ws_size,
                              hipStream_t stream) {
  const float* hidden = (const float*)d_in[0];
  // d_in[1]: attention_mask — exactly the causal mask; applied analytically.
  const int* pos_ids = (const int*)d_in[2];
  const float* Wq = (const float*)d_in[3];
  const float* Wk = (const float*)d_in[4];
  const float* Wv = (const float*)d_in[5];
  const float* Wo = (const float*)d_in[6];

  char* ws = (char*)d_ws;
  // layout (bytes):
  //   [0, 16.78M)      Xb (f16 X)            -> reused as Vt after QKV gemm
  //   [16.78M, 41.94M) Wqkv_t [6144][2048]   -> reused as Q after QKV gemm
  //   [41.94M, 50.33M) Wo_t [2048][2048]
  //   [50.33M, 100.66M) QKVo [4096][6144]    -> reused as O after rope/vtrans
  //   [100.66M, 117.44M) K [32][2048][128]
  //   [117.44M, 118.5M) cos/sin tables (f32)
  _Float16* Xb    = (_Float16*)(ws + 0);
  _Float16* Wqkvt = (_Float16*)(ws + 16777216);
  _Float16* Wot   = (_Float16*)(ws + 41943040);
  _Float16* QKVo  = (_Float16*)(ws + 50331648);
  _Float16* Kbuf  = (_Float16*)(ws + 100663296);
  float* ct       = (float*)(ws + 117440512);
  float* st       = (float*)(ws + 117964800);
  _Float16* Vtbuf = Xb;     // alias (Xb dead after QKV gemm)
  _Float16* Qbuf  = Wqkvt;  // alias (Wqkv_t dead after QKV gemm)
  _Float16* Obuf  = QKVo;   // alias (QKVo dead after rope + v-transpose)

  cvt_x_kernel<<<8192, 256, 0, stream>>>(hidden, Xb, 2097152);
  dim3 wtg(64, 64);
  wtrans_kernel<<<wtg, 256, 0, stream>>>(Wq, Wqkvt, 2048, 2048);
  wtrans_kernel<<<wtg, 256, 0, stream>>>(Wk, Wqkvt + (size_t)2048 * 2048, 2048, 2048);
  wtrans_kernel<<<wtg, 256, 0, stream>>>(Wv, Wqkvt + (size_t)4096 * 2048, 2048, 2048);
  wtrans_kernel<<<wtg, 256, 0, stream>>>(Wo, Wot, 2048, 2048);
  rope_table_kernel<<<512, 256, 0, stream>>>(ct, st);

  gemm_f16_kernel<false><<<dim3(48, 32), 256, 0, stream>>>(Xb, Wqkvt, QKVo, 4096, 6144, 2048);

  rope_qk_kernel<<<16384, 256, 0, stream>>>(QKVo, pos_ids, ct, st, Qbuf, Kbuf);
  v_transpose_kernel<<<dim3(64, 4, 32), 256, 0, stream>>>(QKVo, Vtbuf);

  attn_kernel<<<dim3(32, 32), 256, 0, stream>>>(Qbuf, Kbuf, Vtbuf, Obuf);

  gemm_f16_kernel<true><<<dim3(16, 32), 256, 0, stream>>>(Obuf, Wot, d_out, 4096, 2048, 2048);
}

// Round 2
// 348.642 us; speedup vs baseline: 1.4909x; 1.4909x over previous
//
#include <hip/hip_runtime.h>

typedef __attribute__((ext_vector_type(4))) float f32x4;
typedef __attribute__((ext_vector_type(8))) _Float16 f16x8;
typedef __attribute__((ext_vector_type(4))) _Float16 f16x4;

#define SEQ 2048
#define DM 2048
#define NQKV 6144

// async global->LDS, 16B per lane. LDS dest must be wave-uniform base + lane*16.
__device__ __forceinline__ void gload16(const _Float16* g, _Float16* l) {
  __builtin_amdgcn_global_load_lds(
      (const __attribute__((address_space(1))) void*)g,
      (__attribute__((address_space(3))) void*)l, 16, 0, 0);
}

// ---------------- elementwise convert f32 -> f16 (vectorized) ----------------
__global__ __launch_bounds__(256) void cvt_x_kernel(const float* __restrict__ X,
                                                    _Float16* __restrict__ Xb, int n4) {
  int i = blockIdx.x * 256 + threadIdx.x;
  if (i < n4) {
    const float4 v = ((const float4*)X)[i];
    f16x4 o;
    o.x = (_Float16)v.x; o.y = (_Float16)v.y; o.z = (_Float16)v.z; o.w = (_Float16)v.w;
    ((f16x4*)Xb)[i] = o;
  }
}

// ---------------- tiled transpose + convert: W[K][N] f32 -> Wt[N][K] f16 -----
__global__ __launch_bounds__(256) void wtrans_kernel(const float* __restrict__ W,
                                                     _Float16* __restrict__ Wt,
                                                     int K, int N) {
  __shared__ float tile[32][33];
  const int n0 = blockIdx.x * 32, k0 = blockIdx.y * 32;
  const int tx = threadIdx.x & 31, ty = threadIdx.x >> 5;  // 32 x 8
#pragma unroll
  for (int i = 0; i < 32; i += 8)
    tile[ty + i][tx] = W[(size_t)(k0 + ty + i) * N + n0 + tx];
  __syncthreads();
#pragma unroll
  for (int i = 0; i < 32; i += 8)
    Wt[(size_t)(n0 + ty + i) * K + k0 + tx] = (_Float16)tile[tx][ty + i];
}

// ---------------- RoPE cos/sin table: [2048 pos][64 freq] --------------------
__global__ __launch_bounds__(256) void rope_table_kernel(float* __restrict__ ct,
                                                         float* __restrict__ st) {
  int i = blockIdx.x * 256 + threadIdx.x;  // 131072
  int pos = i >> 6, f = i & 63;
  float inv = powf(10000.0f, -(float)f / 64.0f);
  float ang = (float)pos * inv;
  ct[i] = cosf(ang);
  st[i] = sinf(ang);
}

// ---------------- GEMM (m97 structure): A[M][K] x Bt[N][K], f16 in ----------
// 128x128 tile, BK=64, 4 waves (2x2), global_load_lds width-16 staging into
// linear [128][64] LDS (m97: ~874 TF @ this structure). XCD-bijective swizzle.
template <bool OUTF32>
__global__ __launch_bounds__(256) void gemm_f16_kernel(const _Float16* __restrict__ A,
                                                       const _Float16* __restrict__ Bt,
                                                       void* __restrict__ Cout,
                                                       int M, int N, int K) {
  __shared__ __align__(16) _Float16 As[128 * 64];
  __shared__ __align__(16) _Float16 Bs[128 * 64];
  // nwg divisible by 8 in all launches here -> simple bijective XCD swizzle
  const int nwg = gridDim.x * gridDim.y;
  const int orig = blockIdx.y * gridDim.x + blockIdx.x;
  const int id = (orig & 7) * (nwg >> 3) + (orig >> 3);
  const int bx = id % gridDim.x, by = id / gridDim.x;
  const int bm = by * 128, bn = bx * 128;
  const int t = threadIdx.x, lane = t & 63;
  const int w = t >> 6, wm = w >> 1, wn = w & 1;
  const int rr = lane & 15, lr4 = lane >> 4;
  f32x4 acc[4][4];
#pragma unroll
  for (int i = 0; i < 4; ++i)
#pragma unroll
    for (int j = 0; j < 4; ++j) acc[i][j] = (f32x4)0.0f;

  for (int kt = 0; kt < K; kt += 64) {
#pragma unroll
    for (int i = 0; i < 4; ++i) {
      const int c = i * 256 + t;         // 1024 16B chunks; c = i*256 + w*64 + lane
      const int row = c >> 3, u = c & 7;
      gload16(&A[(size_t)(bm + row) * K + kt + u * 8], &As[c * 8]);
    }
#pragma unroll
    for (int i = 0; i < 4; ++i) {
      const int c = i * 256 + t;
      const int row = c >> 3, u = c & 7;
      gload16(&Bt[(size_t)(bn + row) * K + kt + u * 8], &Bs[c * 8]);
    }
    __syncthreads();  // compiler drains vmcnt here
#pragma unroll
    for (int kk = 0; kk < 2; ++kk) {
      const int ko = kk * 32 + lr4 * 8;
      f16x8 af[4], bf[4];
#pragma unroll
      for (int i = 0; i < 4; ++i) af[i] = *(const f16x8*)&As[(wm * 64 + i * 16 + rr) * 64 + ko];
#pragma unroll
      for (int j = 0; j < 4; ++j) bf[j] = *(const f16x8*)&Bs[(wn * 64 + j * 16 + rr) * 64 + ko];
#pragma unroll
      for (int i = 0; i < 4; ++i)
#pragma unroll
        for (int j = 0; j < 4; ++j)
          acc[i][j] = __builtin_amdgcn_mfma_f32_16x16x32_f16(af[i], bf[j], acc[i][j], 0, 0, 0);
    }
    __syncthreads();
  }
  const int cr = lr4 * 4, cc = rr;
#pragma unroll
  for (int i = 0; i < 4; ++i)
#pragma unroll
    for (int j = 0; j < 4; ++j) {
      int col = bn + wn * 64 + j * 16 + cc;
#pragma unroll
      for (int r = 0; r < 4; ++r) {
        int row = bm + wm * 64 + i * 16 + cr + r;
        if (OUTF32)
          ((float*)Cout)[(size_t)row * N + col] = acc[i][j][r];
        else
          ((_Float16*)Cout)[(size_t)row * N + col] = (_Float16)acc[i][j][r];
      }
    }
}

// ---------------- RoPE on Q,K (from QKV gemm out), scale folded into Q -------
__global__ __launch_bounds__(256) void rope_qk_kernel(const _Float16* __restrict__ QKVo,
                                                      const int* __restrict__ pos_ids,
                                                      const float* __restrict__ ct,
                                                      const float* __restrict__ st,
                                                      _Float16* __restrict__ Q,
                                                      _Float16* __restrict__ K) {
  int id = blockIdx.x * 256 + threadIdx.x;  // 2^22 = B*S*H*64
  int f = id & 63;
  int h = (id >> 6) & 15;
  int s_ = (id >> 10) & 2047;
  int b = (id >> 21) & 1;
  int row = b * SEQ + s_;
  int pos = pos_ids[row];
  float c = ct[pos * 64 + f], sn = st[pos * 64 + f];
  size_t base = (size_t)row * NQKV;
  float q1 = (float)QKVo[base + h * 128 + f];
  float q2 = (float)QKVo[base + h * 128 + f + 64];
  float k1 = (float)QKVo[base + 2048 + h * 128 + f];
  float k2 = (float)QKVo[base + 2048 + h * 128 + f + 64];
  const float scale = 0.08838834764831845f;  // 1/sqrt(128)
  size_t obase = (((size_t)(b * 16 + h)) * SEQ + s_) * 128;
  Q[obase + f]      = (_Float16)((q1 * c - q2 * sn) * scale);
  Q[obase + f + 64] = (_Float16)((q2 * c + q1 * sn) * scale);
  K[obase + f]      = (_Float16)(k1 * c - k2 * sn);
  K[obase + f + 64] = (_Float16)(k2 * c + k1 * sn);
}

// ---------------- V transpose: QKVo v-part -> Vt[bh][128][S] -----------------
__global__ __launch_bounds__(256) void v_transpose_kernel(const _Float16* __restrict__ QKVo,
                                                          _Float16* __restrict__ Vt) {
  __shared__ _Float16 tile[32][40];
  const int s0 = blockIdx.x * 32, d0 = blockIdx.y * 32, bh = blockIdx.z;
  const int b = bh >> 4, h = bh & 15;
  const int tx = threadIdx.x & 31, ty = threadIdx.x >> 5;
#pragma unroll
  for (int i = 0; i < 32; i += 8) {
    int s_ = s0 + ty + i;
    tile[ty + i][tx] = QKVo[(size_t)(b * SEQ + s_) * NQKV + 4096 + h * 128 + d0 + tx];
  }
  __syncthreads();
#pragma unroll
  for (int i = 0; i < 32; i += 8) {
    int d = d0 + ty + i;
    Vt[((size_t)bh * 128 + d) * SEQ + s0 + tx] = tile[tx][ty + i];
  }
}

// ---------------- flash attention, causal, pair-balanced ---------------------
// Block = (bh, pair). Processes q-tiles j=pair and j=15-pair (128 rows each,
// 8 waves x 16 rows) -> every block does exactly 34 K-tile iterations.
// K/V staged via global_load_lds with XOR swizzle (linear LDS dest +
// inverse-swizzled global source), double-buffered, 1 barrier per tile.
__global__ __launch_bounds__(512) void attn_kernel(const _Float16* __restrict__ Q,
                                                   const _Float16* __restrict__ K,
                                                   const _Float16* __restrict__ Vt,
                                                   _Float16* __restrict__ O) {
  __shared__ __align__(16) _Float16 Ks[2][64 * 128];   // [key][dim], swizzled
  __shared__ __align__(16) _Float16 Vs[2][128 * 64];   // [dim][key], swizzled
  __shared__ __align__(16) _Float16 Ps[8][16 * 72];    // per-wave P round-trip
  const int bh = blockIdx.x;    // 0..31; bh%8 -> XCD: one head's K/V stays in one L2
  const int pair = blockIdx.y;  // 0..7
  const int b = bh >> 4, h = bh & 15;
  const int t = threadIdx.x, lane = t & 63, w = t >> 6;
  const int lr = lane >> 4, lc = lane & 15;
  const _Float16* Qb = Q + (size_t)bh * SEQ * 128;
  const _Float16* Kb = K + (size_t)bh * SEQ * 128;
  const _Float16* Vb = Vt + (size_t)bh * 128 * SEQ;

  // stage K-tile [64][128] and V-tile [128][64] for key block kb into buf
  auto stage = [&](int buf, int kb) {
    const int k0 = kb * 64;
#pragma unroll
    for (int i = 0; i < 2; ++i) {
      const int c = i * 512 + t;             // 1024 chunks, c = i*512 + w*64 + lane
      const int row = c >> 4, u = c & 15;    // inverse-swizzle the SOURCE (rule #21)
      gload16(&Kb[(size_t)(k0 + row) * 128 + ((u ^ (row & 7)) * 8)], &Ks[buf][c * 8]);
    }
#pragma unroll
    for (int i = 0; i < 2; ++i) {
      const int c = i * 512 + t;
      const int dim = c >> 3, u = c & 7;
      gload16(&Vb[(size_t)dim * SEQ + k0 + ((u ^ (dim & 7)) * 8)], &Vs[buf][c * 8]);
    }
  };

  for (int half = 0; half < 2; ++half) {
    const int j = half ? (15 - pair) : pair;
    const int q0 = j * 128;
    const int nkb = 2 * j + 2;  // even -> last tile uses buf1, next half stages buf0
    const int rowmin = q0 + w * 16;

    f16x8 qf[4];
    {
      const int qrow = q0 + w * 16 + lc;
#pragma unroll
      for (int kk = 0; kk < 4; ++kk)
        qf[kk] = *(const f16x8*)&Qb[(size_t)qrow * 128 + kk * 32 + lr * 8];
    }
    f32x4 acco[8];
#pragma unroll
    for (int i = 0; i < 8; ++i) acco[i] = (f32x4)0.0f;
    float m_r[4] = {-1e30f, -1e30f, -1e30f, -1e30f};
    float l_r[4] = {0.f, 0.f, 0.f, 0.f};

    stage(0, 0);
    __syncthreads();
    for (int kb = 0; kb < nkb; ++kb) {
      const int cur = kb & 1;
      if (kb + 1 < nkb) stage(cur ^ 1, kb + 1);  // prefetch next; lands by next barrier
      const int k0 = kb * 64;
      if (k0 <= rowmin + 15) {  // skip fully-masked tiles for this wave
        // S = Q K^T (16 q-rows x 64 keys per wave)
        f32x4 sacc[4];
#pragma unroll
        for (int jj = 0; jj < 4; ++jj) sacc[jj] = (f32x4)0.0f;
#pragma unroll
        for (int jj = 0; jj < 4; ++jj) {
          const int krow = jj * 16 + lc;
#pragma unroll
          for (int kk = 0; kk < 4; ++kk) {
            const int idx = (krow * 128 + kk * 32 + lr * 8) ^ ((krow & 7) << 3);
            f16x8 kf = *(const f16x8*)&Ks[cur][idx];
            sacc[jj] = __builtin_amdgcn_mfma_f32_16x16x32_f16(qf[kk], kf, sacc[jj], 0, 0, 0);
          }
        }
        const bool diag = (k0 + 63 > rowmin);
#pragma unroll
        for (int r = 0; r < 4; ++r) {
          const int rowi = rowmin + lr * 4 + r;
          float s[4], mx = -1e30f;
#pragma unroll
          for (int jj = 0; jj < 4; ++jj) {
            float sv = sacc[jj][r];
            if (diag && (k0 + jj * 16 + lc > rowi)) sv = -1e30f;
            s[jj] = sv;
            mx = fmaxf(mx, sv);
          }
#pragma unroll
          for (int msk = 1; msk < 16; msk <<= 1) mx = fmaxf(mx, __shfl_xor(mx, msk));
          const float mn = fmaxf(m_r[r], mx);
          const float sc = __expf(m_r[r] - mn);
          float rs = 0.f;
#pragma unroll
          for (int jj = 0; jj < 4; ++jj) {
            float pv = __expf(s[jj] - mn);
            rs += pv;
            Ps[w][(lr * 4 + r) * 72 + jj * 16 + lc] = (_Float16)pv;
          }
#pragma unroll
          for (int msk = 1; msk < 16; msk <<= 1) rs += __shfl_xor(rs, msk);
          l_r[r] = l_r[r] * sc + rs;
          m_r[r] = mn;
#pragma unroll
          for (int tt = 0; tt < 8; ++tt) acco[tt][r] *= sc;
        }
        // O += P V  (P: 16x64, V^T: 128x64)
#pragma unroll
        for (int tt = 0; tt < 8; ++tt) {
          const int dim = tt * 16 + lc;
#pragma unroll
          for (int ch = 0; ch < 2; ++ch) {
            f16x8 pf = *(const f16x8*)&Ps[w][lc * 72 + ch * 32 + lr * 8];
            const int vidx = (dim * 64 + ch * 32 + lr * 8) ^ ((dim & 7) << 3);
            f16x8 vf = *(const f16x8*)&Vs[cur][vidx];
            acco[tt] = __builtin_amdgcn_mfma_f32_16x16x32_f16(pf, vf, acco[tt], 0, 0, 0);
          }
        }
      }
      __syncthreads();  // drains prefetch vmcnt + guards buffer reuse
    }
    // epilogue
#pragma unroll
    for (int tt = 0; tt < 8; ++tt) {
      const int col = h * 128 + tt * 16 + lc;
#pragma unroll
      for (int r = 0; r < 4; ++r) {
        const int row = q0 + w * 16 + lr * 4 + r;
        O[(size_t)(b * SEQ + row) * DM + col] = (_Float16)(acco[tt][r] / l_r[r]);
      }
    }
  }
}

// ---------------- launch ------------------------------------------------------
extern "C" void kernel_launch(void* const* d_in, const int* in_sizes, int n_in,
                              void* d_out, int out_size, void* d_ws, size_t ws_size,
                              hipStream_t stream) {
  const float* hidden = (const float*)d_in[0];
  // d_in[1]: attention_mask — exactly the causal mask; applied analytically.
  const int* pos_ids = (const int*)d_in[2];
  const float* Wq = (const float*)d_in[3];
  const float* Wk = (const float*)d_in[4];
  const float* Wv = (const float*)d_in[5];
  const float* Wo = (const float*)d_in[6];

  char* ws = (char*)d_ws;
  _Float16* Xb    = (_Float16*)(ws + 0);
  _Float16* Wqkvt = (_Float16*)(ws + 16777216);
  _Float16* Wot   = (_Float16*)(ws + 41943040);
  _Float16* QKVo  = (_Float16*)(ws + 50331648);
  _Float16* Kbuf  = (_Float16*)(ws + 100663296);
  float* ct       = (float*)(ws + 117440512);
  float* st       = (float*)(ws + 117964800);
  _Float16* Vtbuf = Xb;     // alias (Xb dead after QKV gemm)
  _Float16* Qbuf  = Wqkvt;  // alias (Wqkv_t dead after QKV gemm)
  _Float16* Obuf  = QKVo;   // alias (QKVo dead after rope + v-transpose)

  cvt_x_kernel<<<8192, 256, 0, stream>>>(hidden, Xb, 2097152);
  dim3 wtg(64, 64);
  wtrans_kernel<<<wtg, 256, 0, stream>>>(Wq, Wqkvt, 2048, 2048);
  wtrans_kernel<<<wtg, 256, 0, stream>>>(Wk, Wqkvt + (size_t)2048 * 2048, 2048, 2048);
  wtrans_kernel<<<wtg, 256, 0, stream>>>(Wv, Wqkvt + (size_t)4096 * 2048, 2048, 2048);
  wtrans_kernel<<<wtg, 256, 0, stream>>>(Wo, Wot, 2048, 2048);
  rope_table_kernel<<<512, 256, 0, stream>>>(ct, st);

  gemm_f16_kernel<false><<<dim3(48, 32), 256, 0, stream>>>(Xb, Wqkvt, QKVo, 4096, 6144, 2048);

  rope_qk_kernel<<<16384, 256, 0, stream>>>(QKVo, pos_ids, ct, st, Qbuf, Kbuf);
  v_transpose_kernel<<<dim3(64, 4, 32), 256, 0, stream>>>(QKVo, Vtbuf);

  attn_kernel<<<dim3(32, 8), 512, 0, stream>>>(Qbuf, Kbuf, Vtbuf, Obuf);

  gemm_f16_kernel<true><<<dim3(16, 32), 256, 0, stream>>>(Obuf, Wot, d_out, 4096, 2048, 2048);
}

// Round 3
// 347.022 us; speedup vs baseline: 1.4979x; 1.0047x over previous
//
#include <hip/hip_runtime.h>

typedef __attribute__((ext_vector_type(4))) float f32x4;
typedef __attribute__((ext_vector_type(8))) _Float16 f16x8;
typedef __attribute__((ext_vector_type(4))) _Float16 f16x4;

#define SEQ 2048
#define DM 2048
#define NQKV 6144

template <int N> struct IC { static constexpr int value = N; };

// async global->LDS, 16B per lane. LDS dest must be wave-uniform base + lane*16.
__device__ __forceinline__ void gload16(const _Float16* g, _Float16* l) {
  __builtin_amdgcn_global_load_lds(
      (const __attribute__((address_space(1))) void*)g,
      (__attribute__((address_space(3))) void*)l, 16, 0, 0);
}

template <int VM>
__device__ __forceinline__ void waitvm() {
  if constexpr (VM == 9) asm volatile("s_waitcnt vmcnt(9)" ::: "memory");
  else if constexpr (VM == 6) asm volatile("s_waitcnt vmcnt(6)" ::: "memory");
  else if constexpr (VM == 3) asm volatile("s_waitcnt vmcnt(3)" ::: "memory");
  else if constexpr (VM == 0) asm volatile("s_waitcnt vmcnt(0)" ::: "memory");
}

// ---------------- elementwise convert f32 -> f16 (vectorized) ----------------
__global__ __launch_bounds__(256) void cvt_x_kernel(const float* __restrict__ X,
                                                    _Float16* __restrict__ Xb, int n4) {
  int i = blockIdx.x * 256 + threadIdx.x;
  if (i < n4) {
    const float4 v = ((const float4*)X)[i];
    f16x4 o;
    o.x = (_Float16)v.x; o.y = (_Float16)v.y; o.z = (_Float16)v.z; o.w = (_Float16)v.w;
    ((f16x4*)Xb)[i] = o;
  }
}

// ------- fused tiled transpose + convert of all 4 weights (z-indexed) --------
__global__ __launch_bounds__(256) void wtrans_all_kernel(const float* __restrict__ Wq,
                                                         const float* __restrict__ Wk,
                                                         const float* __restrict__ Wv,
                                                         const float* __restrict__ Wo,
                                                         _Float16* __restrict__ Wqkvt,
                                                         _Float16* __restrict__ Wot) {
  __shared__ float tile[32][33];
  const int z = blockIdx.z;
  const float* W = (z == 0) ? Wq : (z == 1) ? Wk : (z == 2) ? Wv : Wo;
  _Float16* Wt = (z < 3) ? (Wqkvt + (size_t)z * 2048 * 2048) : Wot;
  const int n0 = blockIdx.x * 32, k0 = blockIdx.y * 32;
  const int tx = threadIdx.x & 31, ty = threadIdx.x >> 5;  // 32 x 8
#pragma unroll
  for (int i = 0; i < 32; i += 8)
    tile[ty + i][tx] = W[(size_t)(k0 + ty + i) * 2048 + n0 + tx];
  __syncthreads();
#pragma unroll
  for (int i = 0; i < 32; i += 8)
    Wt[(size_t)(n0 + ty + i) * 2048 + k0 + tx] = (_Float16)tile[tx][ty + i];
}

// ---------------- RoPE cos/sin table: [2048 pos][64 freq] --------------------
__global__ __launch_bounds__(256) void rope_table_kernel(float* __restrict__ ct,
                                                         float* __restrict__ st) {
  int i = blockIdx.x * 256 + threadIdx.x;  // 131072
  int pos = i >> 6, f = i & 63;
  float inv = powf(10000.0f, -(float)f / 64.0f);
  float ang = (float)pos * inv;
  ct[i] = cosf(ang);
  st[i] = sinf(ang);
}

// ---------------- GEMM v2: phase-pipelined, counted-vmcnt --------------------
// A[M][K] f16 row-major, Bt[N][K] f16 row-major. BM=256, BN=128, BK=32.
// 8 waves (4M x 2N), per-wave 64x64 C. 5-slot LDS ring (120 KB), stages issued
// 4 tiles ahead, vmcnt(9) steady-state (never 0 in main loop), XOR-swizzled
// tiles (inverse-swizzled global src + swizzled ds_read). One barrier/phase.
template <bool OUTF32>
__global__ __launch_bounds__(512, 2) void gemm2_kernel(const _Float16* __restrict__ A,
                                                       const _Float16* __restrict__ Bt,
                                                       void* __restrict__ Cout,
                                                       int M, int N, int K) {
  __shared__ __align__(16) _Float16 As[5][256 * 32];  // 16 KB/slot
  __shared__ __align__(16) _Float16 Bs[5][128 * 32];  // 8 KB/slot
  // bijective XCD swizzle (all grids here have nwg % 8 == 0)
  const int nwg = gridDim.x * gridDim.y;
  const int orig = blockIdx.y * gridDim.x + blockIdx.x;
  const int id = (orig & 7) * (nwg >> 3) + (orig >> 3);
  const int bx = id % gridDim.x, by = id / gridDim.x;
  const int bm = by * 256, bn = bx * 128;
  const int t = threadIdx.x, lane = t & 63, w = t >> 6;
  const int wm = w >> 1, wn = w & 1;          // 4 x 2 wave grid
  const int rl = lane & 15, lr4 = lane >> 4;  // fragment row / k-chunk
  const int NT = K >> 5;                      // 64 K-slots of 32

  // per-thread staging addresses (chunk = 16B = 8 f16; 4 chunks per 32-f16 row)
  const int cA0 = t, cA1 = 512 + t;
  const int rowA0 = cA0 >> 2, uA0 = cA0 & 3;
  const int rowA1 = cA1 >> 2, uA1 = cA1 & 3;
  const int rowB0 = t >> 2, uB0 = t & 3;
  const _Float16* gA0 = A + (size_t)(bm + rowA0) * K + ((uA0 ^ ((rowA0 >> 1) & 3)) << 3);
  const _Float16* gA1 = A + (size_t)(bm + rowA1) * K + ((uA1 ^ ((rowA1 >> 1) & 3)) << 3);
  const _Float16* gB0 = Bt + (size_t)(bn + rowB0) * K + ((uB0 ^ ((rowB0 >> 1) & 3)) << 3);
  _Float16* lA0 = &As[0][0] + cA0 * 8;
  _Float16* lA1 = &As[0][0] + cA1 * 8;
  _Float16* lB0 = &Bs[0][0] + t * 8;

  auto stage = [&](int s, int rs) {
    gload16(gA0 + s * 32, lA0 + rs * 8192);
    gload16(gA1 + s * 32, lA1 + rs * 8192);
    gload16(gB0 + s * 32, lB0 + rs * 4096);
  };

  f32x4 acc[4][4];
#pragma unroll
  for (int m = 0; m < 4; ++m)
#pragma unroll
    for (int j = 0; j < 4; ++j) acc[m][j] = (f32x4)0.0f;

  // prologue: stage slots 0..3, ensure slot 0 landed (counted: 9 remain)
  stage(0, 0); stage(1, 1); stage(2, 2); stage(3, 3);
  waitvm<9>();
  __builtin_amdgcn_sched_barrier(0);
  __builtin_amdgcn_s_barrier();
  __builtin_amdgcn_sched_barrier(0);

  auto phase = [&](int tile, int r_, auto vmtag, bool do_stage) {
    constexpr int VM = decltype(vmtag)::value;
    if (do_stage) {
      const int rs = r_ ? r_ - 1 : 4;  // (tile+4) % 5
      stage(tile + 4, rs);
    }
    const _Float16* Asl = &As[0][0] + r_ * 8192;
    const _Float16* Bsl = &Bs[0][0] + r_ * 4096;
    f16x8 af[4], bf[4];
#pragma unroll
    for (int m = 0; m < 4; ++m) {
      const int row = wm * 64 + m * 16 + rl;
      af[m] = *(const f16x8*)&Asl[row * 32 + ((lr4 ^ ((row >> 1) & 3)) << 3)];
    }
#pragma unroll
    for (int j = 0; j < 4; ++j) {
      const int row = wn * 64 + j * 16 + rl;
      bf[j] = *(const f16x8*)&Bsl[row * 32 + ((lr4 ^ ((row >> 1) & 3)) << 3)];
    }
    if constexpr (VM >= 0) {
      waitvm<VM>();                       // next slot guaranteed after barrier
      __builtin_amdgcn_sched_barrier(0);
      __builtin_amdgcn_s_barrier();
      __builtin_amdgcn_sched_barrier(0);
    }
    __builtin_amdgcn_s_setprio(1);
#pragma unroll
    for (int m = 0; m < 4; ++m)
#pragma unroll
      for (int j = 0; j < 4; ++j)
        acc[m][j] = __builtin_amdgcn_mfma_f32_16x16x32_f16(af[m], bf[j], acc[m][j], 0, 0, 0);
    __builtin_amdgcn_s_setprio(0);
  };

  int r = 0;
  for (int tile = 0; tile < NT - 4; ++tile) {  // steady state: vmcnt(9), stage t+4
    phase(tile, r, IC<9>{}, true);
    r = (r == 4) ? 0 : r + 1;
  }
  phase(NT - 4, r, IC<6>{}, false); r = (r == 4) ? 0 : r + 1;  // epilogue drain
  phase(NT - 3, r, IC<3>{}, false); r = (r == 4) ? 0 : r + 1;
  phase(NT - 2, r, IC<0>{}, false); r = (r == 4) ? 0 : r + 1;
  phase(NT - 1, r, IC<-1>{}, false);

  // C write: frag row = lr4*4 + ri, col = rl (verified mapping)
#pragma unroll
  for (int m = 0; m < 4; ++m)
#pragma unroll
    for (int j = 0; j < 4; ++j) {
      const int col = bn + wn * 64 + j * 16 + rl;
#pragma unroll
      for (int ri = 0; ri < 4; ++ri) {
        const int row = bm + wm * 64 + m * 16 + lr4 * 4 + ri;
        if (OUTF32)
          ((float*)Cout)[(size_t)row * N + col] = acc[m][j][ri];
        else
          ((_Float16*)Cout)[(size_t)row * N + col] = (_Float16)acc[m][j][ri];
      }
    }
}

// ---------------- RoPE on Q,K (from QKV gemm out), scale folded into Q -------
__global__ __launch_bounds__(256) void rope_qk_kernel(const _Float16* __restrict__ QKVo,
                                                      const int* __restrict__ pos_ids,
                                                      const float* __restrict__ ct,
                                                      const float* __restrict__ st,
                                                      _Float16* __restrict__ Q,
                                                      _Float16* __restrict__ K) {
  int id = blockIdx.x * 256 + threadIdx.x;  // 2^22 = B*S*H*64
  int f = id & 63;
  int h = (id >> 6) & 15;
  int s_ = (id >> 10) & 2047;
  int b = (id >> 21) & 1;
  int row = b * SEQ + s_;
  int pos = pos_ids[row];
  float c = ct[pos * 64 + f], sn = st[pos * 64 + f];
  size_t base = (size_t)row * NQKV;
  float q1 = (float)QKVo[base + h * 128 + f];
  float q2 = (float)QKVo[base + h * 128 + f + 64];
  float k1 = (float)QKVo[base + 2048 + h * 128 + f];
  float k2 = (float)QKVo[base + 2048 + h * 128 + f + 64];
  const float scale = 0.08838834764831845f;  // 1/sqrt(128)
  size_t obase = (((size_t)(b * 16 + h)) * SEQ + s_) * 128;
  Q[obase + f]      = (_Float16)((q1 * c - q2 * sn) * scale);
  Q[obase + f + 64] = (_Float16)((q2 * c + q1 * sn) * scale);
  K[obase + f]      = (_Float16)(k1 * c - k2 * sn);
  K[obase + f + 64] = (_Float16)(k2 * c + k1 * sn);
}

// ---------------- V transpose: QKVo v-part -> Vt[bh][128][S] -----------------
__global__ __launch_bounds__(256) void v_transpose_kernel(const _Float16* __restrict__ QKVo,
                                                          _Float16* __restrict__ Vt) {
  __shared__ _Float16 tile[32][40];
  const int s0 = blockIdx.x * 32, d0 = blockIdx.y * 32, bh = blockIdx.z;
  const int b = bh >> 4, h = bh & 15;
  const int tx = threadIdx.x & 31, ty = threadIdx.x >> 5;
#pragma unroll
  for (int i = 0; i < 32; i += 8) {
    int s_ = s0 + ty + i;
    tile[ty + i][tx] = QKVo[(size_t)(b * SEQ + s_) * NQKV + 4096 + h * 128 + d0 + tx];
  }
  __syncthreads();
#pragma unroll
  for (int i = 0; i < 32; i += 8) {
    int d = d0 + ty + i;
    Vt[((size_t)bh * 128 + d) * SEQ + s0 + tx] = tile[tx][ty + i];
  }
}

// ---------------- flash attention, causal, pair-balanced ---------------------
__global__ __launch_bounds__(512) void attn_kernel(const _Float16* __restrict__ Q,
                                                   const _Float16* __restrict__ K,
                                                   const _Float16* __restrict__ Vt,
                                                   _Float16* __restrict__ O) {
  __shared__ __align__(16) _Float16 Ks[2][64 * 128];   // [key][dim], swizzled
  __shared__ __align__(16) _Float16 Vs[2][128 * 64];   // [dim][key], swizzled
  __shared__ __align__(16) _Float16 Ps[8][16 * 72];    // per-wave P round-trip
  const int bh = blockIdx.x;    // 0..31; bh%8 -> XCD: one head's K/V stays in one L2
  const int pair = blockIdx.y;  // 0..7
  const int b = bh >> 4, h = bh & 15;
  const int t = threadIdx.x, lane = t & 63, w = t >> 6;
  const int lr = lane >> 4, lc = lane & 15;
  const _Float16* Qb = Q + (size_t)bh * SEQ * 128;
  const _Float16* Kb = K + (size_t)bh * SEQ * 128;
  const _Float16* Vb = Vt + (size_t)bh * 128 * SEQ;

  auto stage = [&](int buf, int kb) {
    const int k0 = kb * 64;
#pragma unroll
    for (int i = 0; i < 2; ++i) {
      const int c = i * 512 + t;
      const int row = c >> 4, u = c & 15;
      gload16(&Kb[(size_t)(k0 + row) * 128 + ((u ^ (row & 7)) * 8)], &Ks[buf][c * 8]);
    }
#pragma unroll
    for (int i = 0; i < 2; ++i) {
      const int c = i * 512 + t;
      const int dim = c >> 3, u = c & 7;
      gload16(&Vb[(size_t)dim * SEQ + k0 + ((u ^ (dim & 7)) * 8)], &Vs[buf][c * 8]);
    }
  };

  for (int half = 0; half < 2; ++half) {
    const int j = half ? (15 - pair) : pair;
    const int q0 = j * 128;
    const int nkb = 2 * j + 2;
    const int rowmin = q0 + w * 16;

    f16x8 qf[4];
    {
      const int qrow = q0 + w * 16 + lc;
#pragma unroll
      for (int kk = 0; kk < 4; ++kk)
        qf[kk] = *(const f16x8*)&Qb[(size_t)qrow * 128 + kk * 32 + lr * 8];
    }
    f32x4 acco[8];
#pragma unroll
    for (int i = 0; i < 8; ++i) acco[i] = (f32x4)0.0f;
    float m_r[4] = {-1e30f, -1e30f, -1e30f, -1e30f};
    float l_r[4] = {0.f, 0.f, 0.f, 0.f};

    stage(0, 0);
    __syncthreads();
    for (int kb = 0; kb < nkb; ++kb) {
      const int cur = kb & 1;
      if (kb + 1 < nkb) stage(cur ^ 1, kb + 1);
      const int k0 = kb * 64;
      if (k0 <= rowmin + 15) {
        f32x4 sacc[4];
#pragma unroll
        for (int jj = 0; jj < 4; ++jj) sacc[jj] = (f32x4)0.0f;
#pragma unroll
        for (int jj = 0; jj < 4; ++jj) {
          const int krow = jj * 16 + lc;
#pragma unroll
          for (int kk = 0; kk < 4; ++kk) {
            const int idx = (krow * 128 + kk * 32 + lr * 8) ^ ((krow & 7) << 3);
            f16x8 kf = *(const f16x8*)&Ks[cur][idx];
            sacc[jj] = __builtin_amdgcn_mfma_f32_16x16x32_f16(qf[kk], kf, sacc[jj], 0, 0, 0);
          }
        }
        const bool diag = (k0 + 63 > rowmin);
#pragma unroll
        for (int r = 0; r < 4; ++r) {
          const int rowi = rowmin + lr * 4 + r;
          float s[4], mx = -1e30f;
#pragma unroll
          for (int jj = 0; jj < 4; ++jj) {
            float sv = sacc[jj][r];
            if (diag && (k0 + jj * 16 + lc > rowi)) sv = -1e30f;
            s[jj] = sv;
            mx = fmaxf(mx, sv);
          }
#pragma unroll
          for (int msk = 1; msk < 16; msk <<= 1) mx = fmaxf(mx, __shfl_xor(mx, msk));
          const float mn = fmaxf(m_r[r], mx);
          const float sc = __expf(m_r[r] - mn);
          float rs = 0.f;
#pragma unroll
          for (int jj = 0; jj < 4; ++jj) {
            float pv = __expf(s[jj] - mn);
            rs += pv;
            Ps[w][(lr * 4 + r) * 72 + jj * 16 + lc] = (_Float16)pv;
          }
#pragma unroll
          for (int msk = 1; msk < 16; msk <<= 1) rs += __shfl_xor(rs, msk);
          l_r[r] = l_r[r] * sc + rs;
          m_r[r] = mn;
#pragma unroll
          for (int tt = 0; tt < 8; ++tt) acco[tt][r] *= sc;
        }
#pragma unroll
        for (int tt = 0; tt < 8; ++tt) {
          const int dim = tt * 16 + lc;
#pragma unroll
          for (int ch = 0; ch < 2; ++ch) {
            f16x8 pf = *(const f16x8*)&Ps[w][lc * 72 + ch * 32 + lr * 8];
            const int vidx = (dim * 64 + ch * 32 + lr * 8) ^ ((dim & 7) << 3);
            f16x8 vf = *(const f16x8*)&Vs[cur][vidx];
            acco[tt] = __builtin_amdgcn_mfma_f32_16x16x32_f16(pf, vf, acco[tt], 0, 0, 0);
          }
        }
      }
      __syncthreads();
    }
#pragma unroll
    for (int tt = 0; tt < 8; ++tt) {
      const int col = h * 128 + tt * 16 + lc;
#pragma unroll
      for (int r = 0; r < 4; ++r) {
        const int row = q0 + w * 16 + lr * 4 + r;
        O[(size_t)(b * SEQ + row) * DM + col] = (_Float16)(acco[tt][r] / l_r[r]);
      }
    }
  }
}

// ---------------- launch ------------------------------------------------------
extern "C" void kernel_launch(void* const* d_in, const int* in_sizes, int n_in,
                              void* d_out, int out_size, void* d_ws, size_t ws_size,
                              hipStream_t stream) {
  const float* hidden = (const float*)d_in[0];
  // d_in[1]: attention_mask — exactly the causal mask; applied analytically.
  const int* pos_ids = (const int*)d_in[2];
  const float* Wq = (const float*)d_in[3];
  const float* Wk = (const float*)d_in[4];
  const float* Wv = (const float*)d_in[5];
  const float* Wo = (const float*)d_in[6];

  char* ws = (char*)d_ws;
  _Float16* Xb    = (_Float16*)(ws + 0);
  _Float16* Wqkvt = (_Float16*)(ws + 16777216);
  _Float16* Wot   = (_Float16*)(ws + 41943040);
  _Float16* QKVo  = (_Float16*)(ws + 50331648);
  _Float16* Kbuf  = (_Float16*)(ws + 100663296);
  float* ct       = (float*)(ws + 117440512);
  float* st       = (float*)(ws + 117964800);
  _Float16* Vtbuf = Xb;     // alias (Xb dead after QKV gemm)
  _Float16* Qbuf  = Wqkvt;  // alias (Wqkv_t dead after QKV gemm)
  _Float16* Obuf  = QKVo;   // alias (QKVo dead after rope + v-transpose)

  cvt_x_kernel<<<8192, 256, 0, stream>>>(hidden, Xb, 2097152);
  wtrans_all_kernel<<<dim3(64, 64, 4), 256, 0, stream>>>(Wq, Wk, Wv, Wo, Wqkvt, Wot);
  rope_table_kernel<<<512, 256, 0, stream>>>(ct, st);

  // QKV: M=4096, N=6144 -> grid 48x16 = 768 blocks = 3.0 rounds of 256 CUs
  gemm2_kernel<false><<<dim3(48, 16), 512, 0, stream>>>(Xb, Wqkvt, QKVo, 4096, 6144, 2048);

  rope_qk_kernel<<<16384, 256, 0, stream>>>(QKVo, pos_ids, ct, st, Qbuf, Kbuf);
  v_transpose_kernel<<<dim3(64, 4, 32), 256, 0, stream>>>(QKVo, Vtbuf);

  attn_kernel<<<dim3(32, 8), 512, 0, stream>>>(Qbuf, Kbuf, Vtbuf, Obuf);

  // O-proj: M=4096, N=2048 -> grid 16x16 = 256 blocks = 1.0 round
  gemm2_kernel<true><<<dim3(16, 16), 512, 0, stream>>>(Obuf, Wot, d_out, 4096, 2048, 2048);
}

// Round 4
// 313.251 us; speedup vs baseline: 1.6594x; 1.1078x over previous
//
#include <hip/hip_runtime.h>

typedef __attribute__((ext_vector_type(4))) float f32x4;
typedef __attribute__((ext_vector_type(8))) _Float16 f16x8;
typedef __attribute__((ext_vector_type(4))) _Float16 f16x4;

#define SEQ 2048
#define DM 2048
#define NQKV 6144

// async global->LDS, 16B per lane. LDS dest must be wave-uniform base + lane*16.
__device__ __forceinline__ void gload16(const _Float16* g, _Float16* l) {
  __builtin_amdgcn_global_load_lds(
      (const __attribute__((address_space(1))) void*)g,
      (__attribute__((address_space(3))) void*)l, 16, 0, 0);
}

// ---------------- elementwise convert f32 -> f16 (vectorized) ----------------
__global__ __launch_bounds__(256) void cvt_x_kernel(const float* __restrict__ X,
                                                    _Float16* __restrict__ Xb, int n4) {
  int i = blockIdx.x * 256 + threadIdx.x;
  if (i < n4) {
    const float4 v = ((const float4*)X)[i];
    f16x4 o;
    o.x = (_Float16)v.x; o.y = (_Float16)v.y; o.z = (_Float16)v.z; o.w = (_Float16)v.w;
    ((f16x4*)Xb)[i] = o;
  }
}

// ------- fused tiled transpose + convert of all 4 weights (z-indexed) --------
__global__ __launch_bounds__(256) void wtrans_all_kernel(const float* __restrict__ Wq,
                                                         const float* __restrict__ Wk,
                                                         const float* __restrict__ Wv,
                                                         const float* __restrict__ Wo,
                                                         _Float16* __restrict__ Wqkvt,
                                                         _Float16* __restrict__ Wot) {
  __shared__ float tile[32][33];
  const int z = blockIdx.z;
  const float* W = (z == 0) ? Wq : (z == 1) ? Wk : (z == 2) ? Wv : Wo;
  _Float16* Wt = (z < 3) ? (Wqkvt + (size_t)z * 2048 * 2048) : Wot;
  const int n0 = blockIdx.x * 32, k0 = blockIdx.y * 32;
  const int tx = threadIdx.x & 31, ty = threadIdx.x >> 5;  // 32 x 8
#pragma unroll
  for (int i = 0; i < 32; i += 8)
    tile[ty + i][tx] = W[(size_t)(k0 + ty + i) * 2048 + n0 + tx];
  __syncthreads();
#pragma unroll
  for (int i = 0; i < 32; i += 8)
    Wt[(size_t)(n0 + ty + i) * 2048 + k0 + tx] = (_Float16)tile[tx][ty + i];
}

// ---------------- RoPE cos/sin table: [2048 pos][64 freq] --------------------
__global__ __launch_bounds__(256) void rope_table_kernel(float* __restrict__ ct,
                                                         float* __restrict__ st) {
  int i = blockIdx.x * 256 + threadIdx.x;  // 131072
  int pos = i >> 6, f = i & 63;
  float inv = powf(10000.0f, -(float)f / 64.0f);
  float ang = (float)pos * inv;
  ct[i] = cosf(ang);
  st[i] = sinf(ang);
}

// ---------------- GEMM v3: m97-faithful 2-phase ------------------------------
// A[M][K] f16 row-major x Bt[N][K] f16 row-major. 128x128 tile, BK=64,
// 4 waves (2x2), per-wave 64x64 via 16x16x32 MFMA. global_load_lds width-16
// into linear 16KB tiles, XOR chunk swizzle (inverse-swizzled global source +
// swizzled ds_read; validated round 3), 2 barriers/K-tile, 32KB LDS ->
// ~4 blocks/CU so cross-block overlap hides the barrier drain (m97/m114).
template <bool OUTF32>
__global__ __launch_bounds__(256) void gemm3_kernel(const _Float16* __restrict__ A,
                                                    const _Float16* __restrict__ Bt,
                                                    void* __restrict__ Cout,
                                                    int M, int N, int K) {
  __shared__ __align__(16) _Float16 As[128 * 64];
  __shared__ __align__(16) _Float16 Bs[128 * 64];
  // bijective XCD swizzle (all grids here have nwg % 8 == 0)
  const int nwg = gridDim.x * gridDim.y;
  const int orig = blockIdx.y * gridDim.x + blockIdx.x;
  const int id = (orig & 7) * (nwg >> 3) + (orig >> 3);
  const int bx = id % gridDim.x, by = id / gridDim.x;
  const int bm = by * 128, bn = bx * 128;
  const int t = threadIdx.x, lane = t & 63;
  const int w = t >> 6, wm = w >> 1, wn = w & 1;
  const int rl = lane & 15, lr4 = lane >> 4;

  // staging addresses: 1024 chunks of 16B per matrix; chunk c -> row=c>>3, u=c&7
  // global k-offset uses the inverse swizzle (u ^ (row&7)); LDS dest linear.
  const int rowS = t >> 3, uS = t & 7;  // base chunk for i=0 (c = t)
  f32x4 acc[4][4];
#pragma unroll
  for (int i = 0; i < 4; ++i)
#pragma unroll
    for (int j = 0; j < 4; ++j) acc[i][j] = (f32x4)0.0f;

  for (int kt = 0; kt < K; kt += 64) {
#pragma unroll
    for (int i = 0; i < 4; ++i) {
      const int c = i * 256 + t;
      const int row = c >> 3, u = c & 7;
      gload16(&A[(size_t)(bm + row) * K + kt + ((u ^ (row & 7)) << 3)], &As[c * 8]);
    }
#pragma unroll
    for (int i = 0; i < 4; ++i) {
      const int c = i * 256 + t;
      const int row = c >> 3, u = c & 7;
      gload16(&Bt[(size_t)(bn + row) * K + kt + ((u ^ (row & 7)) << 3)], &Bs[c * 8]);
    }
    __syncthreads();  // drains vmcnt (compiler) -> staged data visible
#pragma unroll
    for (int kk = 0; kk < 2; ++kk) {
      f16x8 af[4], bf[4];
#pragma unroll
      for (int i = 0; i < 4; ++i) {
        const int row = wm * 64 + i * 16 + rl;
        af[i] = *(const f16x8*)&As[row * 64 + (((kk * 4 + lr4) ^ (row & 7)) << 3)];
      }
#pragma unroll
      for (int j = 0; j < 4; ++j) {
        const int row = wn * 64 + j * 16 + rl;
        bf[j] = *(const f16x8*)&Bs[row * 64 + (((kk * 4 + lr4) ^ (row & 7)) << 3)];
      }
#pragma unroll
      for (int i = 0; i < 4; ++i)
#pragma unroll
        for (int j = 0; j < 4; ++j)
          acc[i][j] = __builtin_amdgcn_mfma_f32_16x16x32_f16(af[i], bf[j], acc[i][j], 0, 0, 0);
    }
    __syncthreads();  // guard LDS reuse by next stage
  }
  (void)rowS; (void)uS;
#pragma unroll
  for (int i = 0; i < 4; ++i)
#pragma unroll
    for (int j = 0; j < 4; ++j) {
      const int col = bn + wn * 64 + j * 16 + rl;
#pragma unroll
      for (int ri = 0; ri < 4; ++ri) {
        const int row = bm + wm * 64 + i * 16 + lr4 * 4 + ri;
        if (OUTF32)
          ((float*)Cout)[(size_t)row * N + col] = acc[i][j][ri];
        else
          ((_Float16*)Cout)[(size_t)row * N + col] = (_Float16)acc[i][j][ri];
      }
    }
}

// ---------------- RoPE on Q,K (from QKV gemm out), scale folded into Q -------
__global__ __launch_bounds__(256) void rope_qk_kernel(const _Float16* __restrict__ QKVo,
                                                      const int* __restrict__ pos_ids,
                                                      const float* __restrict__ ct,
                                                      const float* __restrict__ st,
                                                      _Float16* __restrict__ Q,
                                                      _Float16* __restrict__ K) {
  int id = blockIdx.x * 256 + threadIdx.x;  // 2^22 = B*S*H*64
  int f = id & 63;
  int h = (id >> 6) & 15;
  int s_ = (id >> 10) & 2047;
  int b = (id >> 21) & 1;
  int row = b * SEQ + s_;
  int pos = pos_ids[row];
  float c = ct[pos * 64 + f], sn = st[pos * 64 + f];
  size_t base = (size_t)row * NQKV;
  float q1 = (float)QKVo[base + h * 128 + f];
  float q2 = (float)QKVo[base + h * 128 + f + 64];
  float k1 = (float)QKVo[base + 2048 + h * 128 + f];
  float k2 = (float)QKVo[base + 2048 + h * 128 + f + 64];
  const float scale = 0.08838834764831845f;  // 1/sqrt(128)
  size_t obase = (((size_t)(b * 16 + h)) * SEQ + s_) * 128;
  Q[obase + f]      = (_Float16)((q1 * c - q2 * sn) * scale);
  Q[obase + f + 64] = (_Float16)((q2 * c + q1 * sn) * scale);
  K[obase + f]      = (_Float16)(k1 * c - k2 * sn);
  K[obase + f + 64] = (_Float16)(k2 * c + k1 * sn);
}

// ---------------- V transpose: QKVo v-part -> Vt[bh][128][S] -----------------
__global__ __launch_bounds__(256) void v_transpose_kernel(const _Float16* __restrict__ QKVo,
                                                          _Float16* __restrict__ Vt) {
  __shared__ _Float16 tile[32][40];
  const int s0 = blockIdx.x * 32, d0 = blockIdx.y * 32, bh = blockIdx.z;
  const int b = bh >> 4, h = bh & 15;
  const int tx = threadIdx.x & 31, ty = threadIdx.x >> 5;
#pragma unroll
  for (int i = 0; i < 32; i += 8) {
    int s_ = s0 + ty + i;
    tile[ty + i][tx] = QKVo[(size_t)(b * SEQ + s_) * NQKV + 4096 + h * 128 + d0 + tx];
  }
  __syncthreads();
#pragma unroll
  for (int i = 0; i < 32; i += 8) {
    int d = d0 + ty + i;
    Vt[((size_t)bh * 128 + d) * SEQ + s0 + tx] = tile[tx][ty + i];
  }
}

// ---------------- flash attention, causal, pair-balanced ---------------------
__global__ __launch_bounds__(512) void attn_kernel(const _Float16* __restrict__ Q,
                                                   const _Float16* __restrict__ K,
                                                   const _Float16* __restrict__ Vt,
                                                   _Float16* __restrict__ O) {
  __shared__ __align__(16) _Float16 Ks[2][64 * 128];   // [key][dim], swizzled
  __shared__ __align__(16) _Float16 Vs[2][128 * 64];   // [dim][key], swizzled
  __shared__ __align__(16) _Float16 Ps[8][16 * 72];    // per-wave P round-trip
  const int bh = blockIdx.x;    // 0..31; bh%8 -> XCD: one head's K/V stays in one L2
  const int pair = blockIdx.y;  // 0..7
  const int b = bh >> 4, h = bh & 15;
  const int t = threadIdx.x, lane = t & 63, w = t >> 6;
  const int lr = lane >> 4, lc = lane & 15;
  const _Float16* Qb = Q + (size_t)bh * SEQ * 128;
  const _Float16* Kb = K + (size_t)bh * SEQ * 128;
  const _Float16* Vb = Vt + (size_t)bh * 128 * SEQ;

  auto stage = [&](int buf, int kb) {
    const int k0 = kb * 64;
#pragma unroll
    for (int i = 0; i < 2; ++i) {
      const int c = i * 512 + t;
      const int row = c >> 4, u = c & 15;
      gload16(&Kb[(size_t)(k0 + row) * 128 + ((u ^ (row & 7)) * 8)], &Ks[buf][c * 8]);
    }
#pragma unroll
    for (int i = 0; i < 2; ++i) {
      const int c = i * 512 + t;
      const int dim = c >> 3, u = c & 7;
      gload16(&Vb[(size_t)dim * SEQ + k0 + ((u ^ (dim & 7)) * 8)], &Vs[buf][c * 8]);
    }
  };

  for (int half = 0; half < 2; ++half) {
    const int j = half ? (15 - pair) : pair;
    const int q0 = j * 128;
    const int nkb = 2 * j + 2;
    const int rowmin = q0 + w * 16;

    f16x8 qf[4];
    {
      const int qrow = q0 + w * 16 + lc;
#pragma unroll
      for (int kk = 0; kk < 4; ++kk)
        qf[kk] = *(const f16x8*)&Qb[(size_t)qrow * 128 + kk * 32 + lr * 8];
    }
    f32x4 acco[8];
#pragma unroll
    for (int i = 0; i < 8; ++i) acco[i] = (f32x4)0.0f;
    float m_r[4] = {-1e30f, -1e30f, -1e30f, -1e30f};
    float l_r[4] = {0.f, 0.f, 0.f, 0.f};

    stage(0, 0);
    __syncthreads();
    for (int kb = 0; kb < nkb; ++kb) {
      const int cur = kb & 1;
      if (kb + 1 < nkb) stage(cur ^ 1, kb + 1);
      const int k0 = kb * 64;
      if (k0 <= rowmin + 15) {
        f32x4 sacc[4];
#pragma unroll
        for (int jj = 0; jj < 4; ++jj) sacc[jj] = (f32x4)0.0f;
#pragma unroll
        for (int jj = 0; jj < 4; ++jj) {
          const int krow = jj * 16 + lc;
#pragma unroll
          for (int kk = 0; kk < 4; ++kk) {
            const int idx = (krow * 128 + kk * 32 + lr * 8) ^ ((krow & 7) << 3);
            f16x8 kf = *(const f16x8*)&Ks[cur][idx];
            sacc[jj] = __builtin_amdgcn_mfma_f32_16x16x32_f16(qf[kk], kf, sacc[jj], 0, 0, 0);
          }
        }
        const bool diag = (k0 + 63 > rowmin);
#pragma unroll
        for (int r = 0; r < 4; ++r) {
          const int rowi = rowmin + lr * 4 + r;
          float s[4], mx = -1e30f;
#pragma unroll
          for (int jj = 0; jj < 4; ++jj) {
            float sv = sacc[jj][r];
            if (diag && (k0 + jj * 16 + lc > rowi)) sv = -1e30f;
            s[jj] = sv;
            mx = fmaxf(mx, sv);
          }
#pragma unroll
          for (int msk = 1; msk < 16; msk <<= 1) mx = fmaxf(mx, __shfl_xor(mx, msk));
          const float mn = fmaxf(m_r[r], mx);
          const float sc = __expf(m_r[r] - mn);
          float rs = 0.f;
#pragma unroll
          for (int jj = 0; jj < 4; ++jj) {
            float pv = __expf(s[jj] - mn);
            rs += pv;
            Ps[w][(lr * 4 + r) * 72 + jj * 16 + lc] = (_Float16)pv;
          }
#pragma unroll
          for (int msk = 1; msk < 16; msk <<= 1) rs += __shfl_xor(rs, msk);
          l_r[r] = l_r[r] * sc + rs;
          m_r[r] = mn;
#pragma unroll
          for (int tt = 0; tt < 8; ++tt) acco[tt][r] *= sc;
        }
#pragma unroll
        for (int tt = 0; tt < 8; ++tt) {
          const int dim = tt * 16 + lc;
#pragma unroll
          for (int ch = 0; ch < 2; ++ch) {
            f16x8 pf = *(const f16x8*)&Ps[w][lc * 72 + ch * 32 + lr * 8];
            const int vidx = (dim * 64 + ch * 32 + lr * 8) ^ ((dim & 7) << 3);
            f16x8 vf = *(const f16x8*)&Vs[cur][vidx];
            acco[tt] = __builtin_amdgcn_mfma_f32_16x16x32_f16(pf, vf, acco[tt], 0, 0, 0);
          }
        }
      }
      __syncthreads();
    }
#pragma unroll
    for (int tt = 0; tt < 8; ++tt) {
      const int col = h * 128 + tt * 16 + lc;
#pragma unroll
      for (int r = 0; r < 4; ++r) {
        const int row = q0 + w * 16 + lr * 4 + r;
        O[(size_t)(b * SEQ + row) * DM + col] = (_Float16)(acco[tt][r] / l_r[r]);
      }
    }
  }
}

// ---------------- launch ------------------------------------------------------
extern "C" void kernel_launch(void* const* d_in, const int* in_sizes, int n_in,
                              void* d_out, int out_size, void* d_ws, size_t ws_size,
                              hipStream_t stream) {
  const float* hidden = (const float*)d_in[0];
  // d_in[1]: attention_mask — exactly the causal mask; applied analytically.
  const int* pos_ids = (const int*)d_in[2];
  const float* Wq = (const float*)d_in[3];
  const float* Wk = (const float*)d_in[4];
  const float* Wv = (const float*)d_in[5];
  const float* Wo = (const float*)d_in[6];

  char* ws = (char*)d_ws;
  _Float16* Xb    = (_Float16*)(ws + 0);
  _Float16* Wqkvt = (_Float16*)(ws + 16777216);
  _Float16* Wot   = (_Float16*)(ws + 41943040);
  _Float16* QKVo  = (_Float16*)(ws + 50331648);
  _Float16* Kbuf  = (_Float16*)(ws + 100663296);
  float* ct       = (float*)(ws + 117440512);
  float* st       = (float*)(ws + 117964800);
  _Float16* Vtbuf = Xb;     // alias (Xb dead after QKV gemm)
  _Float16* Qbuf  = Wqkvt;  // alias (Wqkv_t dead after QKV gemm)
  _Float16* Obuf  = QKVo;   // alias (QKVo dead after rope + v-transpose)

  cvt_x_kernel<<<8192, 256, 0, stream>>>(hidden, Xb, 2097152);
  wtrans_all_kernel<<<dim3(64, 64, 4), 256, 0, stream>>>(Wq, Wk, Wv, Wo, Wqkvt, Wot);
  rope_table_kernel<<<512, 256, 0, stream>>>(ct, st);

  // QKV: M=4096, N=6144 -> grid 48x32 = 1536 blocks (~4/CU resident)
  gemm3_kernel<false><<<dim3(48, 32), 256, 0, stream>>>(Xb, Wqkvt, QKVo, 4096, 6144, 2048);

  rope_qk_kernel<<<16384, 256, 0, stream>>>(QKVo, pos_ids, ct, st, Qbuf, Kbuf);
  v_transpose_kernel<<<dim3(64, 4, 32), 256, 0, stream>>>(QKVo, Vtbuf);

  attn_kernel<<<dim3(32, 8), 512, 0, stream>>>(Qbuf, Kbuf, Vtbuf, Obuf);

  // O-proj: M=4096, N=2048 -> grid 16x32 = 512 blocks
  gemm3_kernel<true><<<dim3(16, 32), 256, 0, stream>>>(Obuf, Wot, d_out, 4096, 2048, 2048);
}

// Round 5
// 303.827 us; speedup vs baseline: 1.7108x; 1.0310x over previous
//
#include <hip/hip_runtime.h>

typedef __attribute__((ext_vector_type(4))) float f32x4;
typedef __attribute__((ext_vector_type(8))) _Float16 f16x8;
typedef __attribute__((ext_vector_type(4))) _Float16 f16x4;

#define SEQ 2048
#define DM 2048
#define NQKV 6144

// async global->LDS, 16B per lane. LDS dest must be wave-uniform base + lane*16.
__device__ __forceinline__ void gload16(const _Float16* g, _Float16* l) {
  __builtin_amdgcn_global_load_lds(
      (const __attribute__((address_space(1))) void*)g,
      (__attribute__((address_space(3))) void*)l, 16, 0, 0);
}

// ---------------- elementwise convert f32 -> f16 (vectorized) ----------------
__global__ __launch_bounds__(256) void cvt_x_kernel(const float* __restrict__ X,
                                                    _Float16* __restrict__ Xb, int n4) {
  int i = blockIdx.x * 256 + threadIdx.x;
  if (i < n4) {
    const float4 v = ((const float4*)X)[i];
    f16x4 o;
    o.x = (_Float16)v.x; o.y = (_Float16)v.y; o.z = (_Float16)v.z; o.w = (_Float16)v.w;
    ((f16x4*)Xb)[i] = o;
  }
}

// ------- fused tiled transpose + convert of all 4 weights (z-indexed) --------
__global__ __launch_bounds__(256) void wtrans_all_kernel(const float* __restrict__ Wq,
                                                         const float* __restrict__ Wk,
                                                         const float* __restrict__ Wv,
                                                         const float* __restrict__ Wo,
                                                         _Float16* __restrict__ Wqkvt,
                                                         _Float16* __restrict__ Wot) {
  __shared__ float tile[32][33];
  const int z = blockIdx.z;
  const float* W = (z == 0) ? Wq : (z == 1) ? Wk : (z == 2) ? Wv : Wo;
  _Float16* Wt = (z < 3) ? (Wqkvt + (size_t)z * 2048 * 2048) : Wot;
  const int n0 = blockIdx.x * 32, k0 = blockIdx.y * 32;
  const int tx = threadIdx.x & 31, ty = threadIdx.x >> 5;  // 32 x 8
#pragma unroll
  for (int i = 0; i < 32; i += 8)
    tile[ty + i][tx] = W[(size_t)(k0 + ty + i) * 2048 + n0 + tx];
  __syncthreads();
#pragma unroll
  for (int i = 0; i < 32; i += 8)
    Wt[(size_t)(n0 + ty + i) * 2048 + k0 + tx] = (_Float16)tile[tx][ty + i];
}

// ---------------- RoPE cos/sin table: [2048 pos][64 freq] --------------------
__global__ __launch_bounds__(256) void rope_table_kernel(float* __restrict__ ct,
                                                         float* __restrict__ st) {
  int i = blockIdx.x * 256 + threadIdx.x;  // 131072
  int pos = i >> 6, f = i & 63;
  float inv = powf(10000.0f, -(float)f / 64.0f);
  float ang = (float)pos * inv;
  ct[i] = cosf(ang);
  st[i] = sinf(ang);
}

// ---------------- GEMM v4: 256x256 8-phase schedule (m201 port, f16) ---------
// A[M][K] x Bt[N][K]. BK=64, 8 waves (2M x 4N), per-wave C = 128x64 scattered
// as 4 quadrant blocks (quadrant <-> LDS half). Per K-tile: 4 phases, each
// {ds_read subtile | stage 1 half-tile | barrier | lgkm0 | setprio+16 MFMA |
// barrier}. Stage stream runs 6 half-tiles ahead; vmcnt(4) once per K-tile
// (positions land exactly the next group's data; never 0 until tail).
// Race-audit: each stage targets a region whose last ds_reads were drained
// >=1 barrier earlier. Raw s_barrier (NOT __syncthreads: would drain vmcnt).
template <bool OUTF32>
__global__ __launch_bounds__(512, 2) void gemm8_kernel(const _Float16* __restrict__ A,
                                                       const _Float16* __restrict__ Bt,
                                                       void* __restrict__ Cout,
                                                       int M, int N, int K) {
  __shared__ __align__(16) _Float16 As[2 * 16384];  // 2 buf x (2 half x 128 x 64)
  __shared__ __align__(16) _Float16 Bs[2 * 16384];
  // bijective XCD swizzle (nwg % 8 == 0 for all launches here)
  const int nwg = gridDim.x * gridDim.y;
  const int orig = blockIdx.y * gridDim.x + blockIdx.x;
  const int id = (orig & 7) * (nwg >> 3) + (orig >> 3);
  const int bx = id % gridDim.x, by = id / gridDim.x;
  const int bm = by * 256, bn = bx * 256;
  const int t = threadIdx.x, lane = t & 63, w = t >> 6;
  const int wm = w >> 2, wn = w & 3;  // 2 (M) x 4 (N) waves
  const int rl = lane & 15, lr4 = lane >> 4;
  const int NKT = K >> 6;

  // staging: thread t covers chunks c=t (rows 0..63) and c=512+t (rows 64..127)
  // of each 128x64 half-tile; XOR chunk swizzle folded into the global source.
  const int srow = t >> 3;
  const int scol = ((t & 7) ^ (srow & 7)) << 3;
  const _Float16* pA = A + (size_t)(bm + srow) * K + scol;
  const _Float16* pB = Bt + (size_t)(bn + srow) * K + scol;
  _Float16* lA = As + t * 8;
  _Float16* lB = Bs + t * 8;
  const size_t rowK64 = (size_t)64 * K;

#define STAGE_A(h, kt)                                                                     \
  { const int _b = (kt) & 1; const size_t _g = (size_t)((h) * 128) * K + (size_t)(kt) * 64; \
    gload16(pA + _g, lA + _b * 16384 + (h) * 8192);                                        \
    gload16(pA + _g + rowK64, lA + _b * 16384 + (h) * 8192 + 4096); }
#define STAGE_B(h, kt)                                                                     \
  { const int _b = (kt) & 1; const size_t _g = (size_t)((h) * 128) * K + (size_t)(kt) * 64; \
    gload16(pB + _g, lB + _b * 16384 + (h) * 8192);                                        \
    gload16(pB + _g + rowK64, lB + _b * 16384 + (h) * 8192 + 4096); }

  const int sw0 = (lr4 ^ (rl & 7)) << 3;
  const int sw1 = ((4 + lr4) ^ (rl & 7)) << 3;
  const int aoff = (wm * 64 + rl) * 64;
  const int boff = (wn * 32 + rl) * 64;

  f16x8 a_[4][2], b0_[2][2], b1_[2][2];
  f32x4 acc[2][2][4][2];  // [qm][qn][mf][nf]
#pragma unroll
  for (int qm = 0; qm < 2; ++qm)
#pragma unroll
    for (int qn = 0; qn < 2; ++qn)
#pragma unroll
      for (int mf = 0; mf < 4; ++mf)
#pragma unroll
        for (int nf = 0; nf < 2; ++nf) acc[qm][qn][mf][nf] = (f32x4)0.0f;

#define LOAD_A(QM, BUF)                                                 \
  { const _Float16* _p = As + (BUF) * 16384 + (QM) * 8192 + aoff;       \
    _Pragma("unroll") for (int mf = 0; mf < 4; ++mf) {                  \
      a_[mf][0] = *(const f16x8*)&_p[mf * 1024 + sw0];                  \
      a_[mf][1] = *(const f16x8*)&_p[mf * 1024 + sw1]; } }
#define LOAD_B(DST, QN, BUF)                                            \
  { const _Float16* _p = Bs + (BUF) * 16384 + (QN) * 8192 + boff;       \
    _Pragma("unroll") for (int nf = 0; nf < 2; ++nf) {                  \
      DST[nf][0] = *(const f16x8*)&_p[nf * 1024 + sw0];                 \
      DST[nf][1] = *(const f16x8*)&_p[nf * 1024 + sw1]; } }
#define MFMA_Q(QM, QN, BREG)                                            \
  __builtin_amdgcn_s_setprio(1);                                        \
  _Pragma("unroll") for (int mf = 0; mf < 4; ++mf)                      \
    _Pragma("unroll") for (int nf = 0; nf < 2; ++nf) {                  \
      acc[QM][QN][mf][nf] = __builtin_amdgcn_mfma_f32_16x16x32_f16(     \
          a_[mf][0], BREG[nf][0], acc[QM][QN][mf][nf], 0, 0, 0);        \
      acc[QM][QN][mf][nf] = __builtin_amdgcn_mfma_f32_16x16x32_f16(     \
          a_[mf][1], BREG[nf][1], acc[QM][QN][mf][nf], 0, 0, 0); }      \
  __builtin_amdgcn_s_setprio(0);
#define BAR()                                                           \
  do { __builtin_amdgcn_sched_barrier(0); __builtin_amdgcn_s_barrier(); \
       __builtin_amdgcn_sched_barrier(0); } while (0)
#define LGKM0()                                                         \
  do { asm volatile("s_waitcnt lgkmcnt(0)" ::: "memory");               \
       __builtin_amdgcn_sched_barrier(0); } while (0)

  // prologue: stage positions 0..5 = [A0,B0,A1,B1](kt0), [A0,B0](kt1)
  STAGE_A(0, 0); STAGE_B(0, 0); STAGE_A(1, 0); STAGE_B(1, 0);
  STAGE_A(0, 1); STAGE_B(0, 1);
  asm volatile("s_waitcnt vmcnt(4)" ::: "memory");  // kt0's 4 half-tiles landed
  BAR();

  for (int j = 0; j < NKT; ++j) {
    const int buf = j & 1;
    // phase 0: quad (0,0) — reads A-h0, B-h0 of buf
    LOAD_A(0, buf); LOAD_B(b0_, 0, buf);
    if (j + 1 < NKT) STAGE_A(1, j + 1);   // other dbuf
    BAR(); LGKM0();
    MFMA_Q(0, 0, b0_);
    BAR();
    // phase 1: quad (0,1) — reads B-h1 of buf
    LOAD_B(b1_, 1, buf);
    if (j + 1 < NKT) STAGE_B(1, j + 1);   // other dbuf
    BAR(); LGKM0();
    MFMA_Q(0, 1, b1_);
    BAR();
    // phase 2: quad (1,0) — reads A-h1 of buf
    LOAD_A(1, buf);
    if (j + 2 < NKT) STAGE_A(0, j + 2);   // same dbuf; A-h0 reads drained @ph0
    BAR(); LGKM0();
    MFMA_Q(1, 0, b0_);
    BAR();
    // phase 3: quad (1,1) — no reads
    if (j + 2 < NKT) STAGE_B(0, j + 2);   // same dbuf; B-h0 reads drained @ph0
    BAR(); LGKM0();
    MFMA_Q(1, 1, b1_);
    if (j < NKT - 2)       { asm volatile("s_waitcnt vmcnt(4)" ::: "memory"); }
    else if (j == NKT - 2) { asm volatile("s_waitcnt vmcnt(0)" ::: "memory"); }
    BAR();
  }

  // C write: row = bm + qm*128 + wm*64 + mf*16 + lr4*4 + ri; col = bn + qn*128 + wn*32 + nf*16 + rl
#pragma unroll
  for (int qm = 0; qm < 2; ++qm)
#pragma unroll
    for (int qn = 0; qn < 2; ++qn)
#pragma unroll
      for (int mf = 0; mf < 4; ++mf)
#pragma unroll
        for (int nf = 0; nf < 2; ++nf) {
          const int col = bn + qn * 128 + wn * 32 + nf * 16 + rl;
#pragma unroll
          for (int ri = 0; ri < 4; ++ri) {
            const int row = bm + qm * 128 + wm * 64 + mf * 16 + lr4 * 4 + ri;
            if (OUTF32)
              ((float*)Cout)[(size_t)row * N + col] = acc[qm][qn][mf][nf][ri];
            else
              ((_Float16*)Cout)[(size_t)row * N + col] = (_Float16)acc[qm][qn][mf][nf][ri];
          }
        }
#undef STAGE_A
#undef STAGE_B
#undef LOAD_A
#undef LOAD_B
#undef MFMA_Q
#undef BAR
#undef LGKM0
}

// ---------------- GEMM v3: m97-faithful 2-phase (kept for O-proj) ------------
template <bool OUTF32>
__global__ __launch_bounds__(256) void gemm3_kernel(const _Float16* __restrict__ A,
                                                    const _Float16* __restrict__ Bt,
                                                    void* __restrict__ Cout,
                                                    int M, int N, int K) {
  __shared__ __align__(16) _Float16 As[128 * 64];
  __shared__ __align__(16) _Float16 Bs[128 * 64];
  const int nwg = gridDim.x * gridDim.y;
  const int orig = blockIdx.y * gridDim.x + blockIdx.x;
  const int id = (orig & 7) * (nwg >> 3) + (orig >> 3);
  const int bx = id % gridDim.x, by = id / gridDim.x;
  const int bm = by * 128, bn = bx * 128;
  const int t = threadIdx.x, lane = t & 63;
  const int w = t >> 6, wm = w >> 1, wn = w & 1;
  const int rl = lane & 15, lr4 = lane >> 4;

  f32x4 acc[4][4];
#pragma unroll
  for (int i = 0; i < 4; ++i)
#pragma unroll
    for (int j = 0; j < 4; ++j) acc[i][j] = (f32x4)0.0f;

  for (int kt = 0; kt < K; kt += 64) {
#pragma unroll
    for (int i = 0; i < 4; ++i) {
      const int c = i * 256 + t;
      const int row = c >> 3, u = c & 7;
      gload16(&A[(size_t)(bm + row) * K + kt + ((u ^ (row & 7)) << 3)], &As[c * 8]);
    }
#pragma unroll
    for (int i = 0; i < 4; ++i) {
      const int c = i * 256 + t;
      const int row = c >> 3, u = c & 7;
      gload16(&Bt[(size_t)(bn + row) * K + kt + ((u ^ (row & 7)) << 3)], &Bs[c * 8]);
    }
    __syncthreads();
#pragma unroll
    for (int kk = 0; kk < 2; ++kk) {
      f16x8 af[4], bf[4];
#pragma unroll
      for (int i = 0; i < 4; ++i) {
        const int row = wm * 64 + i * 16 + rl;
        af[i] = *(const f16x8*)&As[row * 64 + (((kk * 4 + lr4) ^ (row & 7)) << 3)];
      }
#pragma unroll
      for (int j = 0; j < 4; ++j) {
        const int row = wn * 64 + j * 16 + rl;
        bf[j] = *(const f16x8*)&Bs[row * 64 + (((kk * 4 + lr4) ^ (row & 7)) << 3)];
      }
#pragma unroll
      for (int i = 0; i < 4; ++i)
#pragma unroll
        for (int j = 0; j < 4; ++j)
          acc[i][j] = __builtin_amdgcn_mfma_f32_16x16x32_f16(af[i], bf[j], acc[i][j], 0, 0, 0);
    }
    __syncthreads();
  }
#pragma unroll
  for (int i = 0; i < 4; ++i)
#pragma unroll
    for (int j = 0; j < 4; ++j) {
      const int col = bn + wn * 64 + j * 16 + rl;
#pragma unroll
      for (int ri = 0; ri < 4; ++ri) {
        const int row = bm + wm * 64 + i * 16 + lr4 * 4 + ri;
        if (OUTF32)
          ((float*)Cout)[(size_t)row * N + col] = acc[i][j][ri];
        else
          ((_Float16*)Cout)[(size_t)row * N + col] = (_Float16)acc[i][j][ri];
      }
    }
}

// ---------------- RoPE on Q,K (from QKV gemm out), scale folded into Q -------
__global__ __launch_bounds__(256) void rope_qk_kernel(const _Float16* __restrict__ QKVo,
                                                      const int* __restrict__ pos_ids,
                                                      const float* __restrict__ ct,
                                                      const float* __restrict__ st,
                                                      _Float16* __restrict__ Q,
                                                      _Float16* __restrict__ K) {
  int id = blockIdx.x * 256 + threadIdx.x;  // 2^22 = B*S*H*64
  int f = id & 63;
  int h = (id >> 6) & 15;
  int s_ = (id >> 10) & 2047;
  int b = (id >> 21) & 1;
  int row = b * SEQ + s_;
  int pos = pos_ids[row];
  float c = ct[pos * 64 + f], sn = st[pos * 64 + f];
  size_t base = (size_t)row * NQKV;
  float q1 = (float)QKVo[base + h * 128 + f];
  float q2 = (float)QKVo[base + h * 128 + f + 64];
  float k1 = (float)QKVo[base + 2048 + h * 128 + f];
  float k2 = (float)QKVo[base + 2048 + h * 128 + f + 64];
  const float scale = 0.08838834764831845f;  // 1/sqrt(128)
  size_t obase = (((size_t)(b * 16 + h)) * SEQ + s_) * 128;
  Q[obase + f]      = (_Float16)((q1 * c - q2 * sn) * scale);
  Q[obase + f + 64] = (_Float16)((q2 * c + q1 * sn) * scale);
  K[obase + f]      = (_Float16)(k1 * c - k2 * sn);
  K[obase + f + 64] = (_Float16)(k2 * c + k1 * sn);
}

// ---------------- V transpose: QKVo v-part -> Vt[bh][128][S] -----------------
__global__ __launch_bounds__(256) void v_transpose_kernel(const _Float16* __restrict__ QKVo,
                                                          _Float16* __restrict__ Vt) {
  __shared__ _Float16 tile[32][40];
  const int s0 = blockIdx.x * 32, d0 = blockIdx.y * 32, bh = blockIdx.z;
  const int b = bh >> 4, h = bh & 15;
  const int tx = threadIdx.x & 31, ty = threadIdx.x >> 5;
#pragma unroll
  for (int i = 0; i < 32; i += 8) {
    int s_ = s0 + ty + i;
    tile[ty + i][tx] = QKVo[(size_t)(b * SEQ + s_) * NQKV + 4096 + h * 128 + d0 + tx];
  }
  __syncthreads();
#pragma unroll
  for (int i = 0; i < 32; i += 8) {
    int d = d0 + ty + i;
    Vt[((size_t)bh * 128 + d) * SEQ + s0 + tx] = tile[tx][ty + i];
  }
}

// ---------------- flash attention, causal, pair-balanced ---------------------
__global__ __launch_bounds__(512) void attn_kernel(const _Float16* __restrict__ Q,
                                                   const _Float16* __restrict__ K,
                                                   const _Float16* __restrict__ Vt,
                                                   _Float16* __restrict__ O) {
  __shared__ __align__(16) _Float16 Ks[2][64 * 128];   // [key][dim], swizzled
  __shared__ __align__(16) _Float16 Vs[2][128 * 64];   // [dim][key], swizzled
  __shared__ __align__(16) _Float16 Ps[8][16 * 72];    // per-wave P round-trip
  const int bh = blockIdx.x;    // 0..31; bh%8 -> XCD: one head's K/V stays in one L2
  const int pair = blockIdx.y;  // 0..7
  const int b = bh >> 4, h = bh & 15;
  const int t = threadIdx.x, lane = t & 63, w = t >> 6;
  const int lr = lane >> 4, lc = lane & 15;
  const _Float16* Qb = Q + (size_t)bh * SEQ * 128;
  const _Float16* Kb = K + (size_t)bh * SEQ * 128;
  const _Float16* Vb = Vt + (size_t)bh * 128 * SEQ;

  auto stage = [&](int buf, int kb) {
    const int k0 = kb * 64;
#pragma unroll
    for (int i = 0; i < 2; ++i) {
      const int c = i * 512 + t;
      const int row = c >> 4, u = c & 15;
      gload16(&Kb[(size_t)(k0 + row) * 128 + ((u ^ (row & 7)) * 8)], &Ks[buf][c * 8]);
    }
#pragma unroll
    for (int i = 0; i < 2; ++i) {
      const int c = i * 512 + t;
      const int dim = c >> 3, u = c & 7;
      gload16(&Vb[(size_t)dim * SEQ + k0 + ((u ^ (dim & 7)) * 8)], &Vs[buf][c * 8]);
    }
  };

  for (int half = 0; half < 2; ++half) {
    const int j = half ? (15 - pair) : pair;
    const int q0 = j * 128;
    const int nkb = 2 * j + 2;
    const int rowmin = q0 + w * 16;

    f16x8 qf[4];
    {
      const int qrow = q0 + w * 16 + lc;
#pragma unroll
      for (int kk = 0; kk < 4; ++kk)
        qf[kk] = *(const f16x8*)&Qb[(size_t)qrow * 128 + kk * 32 + lr * 8];
    }
    f32x4 acco[8];
#pragma unroll
    for (int i = 0; i < 8; ++i) acco[i] = (f32x4)0.0f;
    float m_r[4] = {-1e30f, -1e30f, -1e30f, -1e30f};
    float l_r[4] = {0.f, 0.f, 0.f, 0.f};

    stage(0, 0);
    __syncthreads();
    for (int kb = 0; kb < nkb; ++kb) {
      const int cur = kb & 1;
      if (kb + 1 < nkb) stage(cur ^ 1, kb + 1);
      const int k0 = kb * 64;
      if (k0 <= rowmin + 15) {
        f32x4 sacc[4];
#pragma unroll
        for (int jj = 0; jj < 4; ++jj) sacc[jj] = (f32x4)0.0f;
#pragma unroll
        for (int jj = 0; jj < 4; ++jj) {
          const int krow = jj * 16 + lc;
#pragma unroll
          for (int kk = 0; kk < 4; ++kk) {
            const int idx = (krow * 128 + kk * 32 + lr * 8) ^ ((krow & 7) << 3);
            f16x8 kf = *(const f16x8*)&Ks[cur][idx];
            sacc[jj] = __builtin_amdgcn_mfma_f32_16x16x32_f16(qf[kk], kf, sacc[jj], 0, 0, 0);
          }
        }
        const bool diag = (k0 + 63 > rowmin);
#pragma unroll
        for (int r = 0; r < 4; ++r) {
          const int rowi = rowmin + lr * 4 + r;
          float s[4], mx = -1e30f;
#pragma unroll
          for (int jj = 0; jj < 4; ++jj) {
            float sv = sacc[jj][r];
            if (diag && (k0 + jj * 16 + lc > rowi)) sv = -1e30f;
            s[jj] = sv;
            mx = fmaxf(mx, sv);
          }
#pragma unroll
          for (int msk = 1; msk < 16; msk <<= 1) mx = fmaxf(mx, __shfl_xor(mx, msk));
          const float mn = fmaxf(m_r[r], mx);
          const float sc = __expf(m_r[r] - mn);
          float rs = 0.f;
#pragma unroll
          for (int jj = 0; jj < 4; ++jj) {
            float pv = __expf(s[jj] - mn);
            rs += pv;
            Ps[w][(lr * 4 + r) * 72 + jj * 16 + lc] = (_Float16)pv;
          }
#pragma unroll
          for (int msk = 1; msk < 16; msk <<= 1) rs += __shfl_xor(rs, msk);
          l_r[r] = l_r[r] * sc + rs;
          m_r[r] = mn;
#pragma unroll
          for (int tt = 0; tt < 8; ++tt) acco[tt][r] *= sc;
        }
#pragma unroll
        for (int tt = 0; tt < 8; ++tt) {
          const int dim = tt * 16 + lc;
#pragma unroll
          for (int ch = 0; ch < 2; ++ch) {
            f16x8 pf = *(const f16x8*)&Ps[w][lc * 72 + ch * 32 + lr * 8];
            const int vidx = (dim * 64 + ch * 32 + lr * 8) ^ ((dim & 7) << 3);
            f16x8 vf = *(const f16x8*)&Vs[cur][vidx];
            acco[tt] = __builtin_amdgcn_mfma_f32_16x16x32_f16(pf, vf, acco[tt], 0, 0, 0);
          }
        }
      }
      __syncthreads();
    }
#pragma unroll
    for (int tt = 0; tt < 8; ++tt) {
      const int col = h * 128 + tt * 16 + lc;
#pragma unroll
      for (int r = 0; r < 4; ++r) {
        const int row = q0 + w * 16 + lr * 4 + r;
        O[(size_t)(b * SEQ + row) * DM + col] = (_Float16)(acco[tt][r] / l_r[r]);
      }
    }
  }
}

// ---------------- launch ------------------------------------------------------
extern "C" void kernel_launch(void* const* d_in, const int* in_sizes, int n_in,
                              void* d_out, int out_size, void* d_ws, size_t ws_size,
                              hipStream_t stream) {
  const float* hidden = (const float*)d_in[0];
  // d_in[1]: attention_mask — exactly the causal mask; applied analytically.
  const int* pos_ids = (const int*)d_in[2];
  const float* Wq = (const float*)d_in[3];
  const float* Wk = (const float*)d_in[4];
  const float* Wv = (const float*)d_in[5];
  const float* Wo = (const float*)d_in[6];

  char* ws = (char*)d_ws;
  _Float16* Xb    = (_Float16*)(ws + 0);
  _Float16* Wqkvt = (_Float16*)(ws + 16777216);
  _Float16* Wot   = (_Float16*)(ws + 41943040);
  _Float16* QKVo  = (_Float16*)(ws + 50331648);
  _Float16* Kbuf  = (_Float16*)(ws + 100663296);
  float* ct       = (float*)(ws + 117440512);
  float* st       = (float*)(ws + 117964800);
  _Float16* Vtbuf = Xb;     // alias (Xb dead after QKV gemm)
  _Float16* Qbuf  = Wqkvt;  // alias (Wqkv_t dead after QKV gemm)
  _Float16* Obuf  = QKVo;   // alias (QKVo dead after rope + v-transpose)

  cvt_x_kernel<<<8192, 256, 0, stream>>>(hidden, Xb, 2097152);
  wtrans_all_kernel<<<dim3(64, 64, 4), 256, 0, stream>>>(Wq, Wk, Wv, Wo, Wqkvt, Wot);
  rope_table_kernel<<<512, 256, 0, stream>>>(ct, st);

  // QKV: M=4096, N=6144 -> grid 24x16 = 384 blocks, 256^2 8-phase
  gemm8_kernel<false><<<dim3(24, 16), 512, 0, stream>>>(Xb, Wqkvt, QKVo, 4096, 6144, 2048);

  rope_qk_kernel<<<16384, 256, 0, stream>>>(QKVo, pos_ids, ct, st, Qbuf, Kbuf);
  v_transpose_kernel<<<dim3(64, 4, 32), 256, 0, stream>>>(QKVo, Vtbuf);

  attn_kernel<<<dim3(32, 8), 512, 0, stream>>>(Qbuf, Kbuf, Vtbuf, Obuf);

  // O-proj: M=4096, N=2048 -> grid 16x32 = 512 blocks (balanced, m97 structure)
  gemm3_kernel<true><<<dim3(16, 32), 256, 0, stream>>>(Obuf, Wot, d_out, 4096, 2048, 2048);
}

// Round 6
// 298.227 us; speedup vs baseline: 1.7430x; 1.0188x over previous
//
#include <hip/hip_runtime.h>

typedef __attribute__((ext_vector_type(4))) float f32x4;
typedef __attribute__((ext_vector_type(8))) _Float16 f16x8;
typedef __attribute__((ext_vector_type(4))) _Float16 f16x4;

#define SEQ 2048
#define DM 2048
#define NQKV 6144

// async global->LDS, 16B per lane. LDS dest must be wave-uniform base + lane*16.
__device__ __forceinline__ void gload16(const _Float16* g, _Float16* l) {
  __builtin_amdgcn_global_load_lds(
      (const __attribute__((address_space(1))) void*)g,
      (__attribute__((address_space(3))) void*)l, 16, 0, 0);
}

// ---------------- elementwise convert f32 -> f16 (vectorized) ----------------
__global__ __launch_bounds__(256) void cvt_x_kernel(const float* __restrict__ X,
                                                    _Float16* __restrict__ Xb, int n4) {
  int i = blockIdx.x * 256 + threadIdx.x;
  if (i < n4) {
    const float4 v = ((const float4*)X)[i];
    f16x4 o;
    o.x = (_Float16)v.x; o.y = (_Float16)v.y; o.z = (_Float16)v.z; o.w = (_Float16)v.w;
    ((f16x4*)Xb)[i] = o;
  }
}

// ------- fused tiled transpose + convert of all 4 weights (z-indexed) --------
__global__ __launch_bounds__(256) void wtrans_all_kernel(const float* __restrict__ Wq,
                                                         const float* __restrict__ Wk,
                                                         const float* __restrict__ Wv,
                                                         const float* __restrict__ Wo,
                                                         _Float16* __restrict__ Wqkvt,
                                                         _Float16* __restrict__ Wot) {
  __shared__ float tile[32][33];
  const int z = blockIdx.z;
  const float* W = (z == 0) ? Wq : (z == 1) ? Wk : (z == 2) ? Wv : Wo;
  _Float16* Wt = (z < 3) ? (Wqkvt + (size_t)z * 2048 * 2048) : Wot;
  const int n0 = blockIdx.x * 32, k0 = blockIdx.y * 32;
  const int tx = threadIdx.x & 31, ty = threadIdx.x >> 5;  // 32 x 8
#pragma unroll
  for (int i = 0; i < 32; i += 8)
    tile[ty + i][tx] = W[(size_t)(k0 + ty + i) * 2048 + n0 + tx];
  __syncthreads();
#pragma unroll
  for (int i = 0; i < 32; i += 8)
    Wt[(size_t)(n0 + ty + i) * 2048 + k0 + tx] = (_Float16)tile[tx][ty + i];
}

// ---------------- RoPE cos/sin table: [2048 pos][64 freq] --------------------
__global__ __launch_bounds__(256) void rope_table_kernel(float* __restrict__ ct,
                                                         float* __restrict__ st) {
  int i = blockIdx.x * 256 + threadIdx.x;  // 131072
  int pos = i >> 6, f = i & 63;
  float inv = powf(10000.0f, -(float)f / 64.0f);
  float ang = (float)pos * inv;
  ct[i] = cosf(ang);
  st[i] = sinf(ang);
}

// ---------------- GEMM v5: 256x256 8-phase, m201-exact loop shape ------------
// Unroll 2 K-tiles/iter (all LDS offsets compile-time), stage stream 7
// half-tiles deep, vmcnt(6) only at phases 4/8 (3 half-tiles in flight),
// reads rebalanced 8/4/8/4 via post-barrier b0_ preload in phases 3/7.
// Race audit: every stage write lands >=1 barrier after its region's last
// ds_read; per-wave vmcnt before barrier => all waves' DMA shares landed.
template <bool OUTF32>
__global__ __launch_bounds__(512, 2) void gemm8_kernel(const _Float16* __restrict__ A,
                                                       const _Float16* __restrict__ Bt,
                                                       void* __restrict__ Cout,
                                                       int M, int N, int K) {
  __shared__ __align__(16) _Float16 As[2 * 16384];  // 2 buf x (2 half x 128 x 64)
  __shared__ __align__(16) _Float16 Bs[2 * 16384];
  const int nwg = gridDim.x * gridDim.y;
  const int orig = blockIdx.y * gridDim.x + blockIdx.x;
  const int id = (orig & 7) * (nwg >> 3) + (orig >> 3);
  const int bx = id % gridDim.x, by = id / gridDim.x;
  const int bm = by * 256, bn = bx * 256;
  const int t = threadIdx.x, lane = t & 63, w = t >> 6;
  const int wm = w >> 2, wn = w & 3;  // 2 (M) x 4 (N) waves
  const int rl = lane & 15, lr4 = lane >> 4;
  const int NKT = K >> 6;  // even, >= 4

  // staging: thread t covers chunk c=t (rows 0..63) and c=512+t (rows 64..127)
  // of each 128x64 half-tile; XOR chunk swizzle folded into global source.
  const int srow = t >> 3;
  const int scol = ((t & 7) ^ (srow & 7)) << 3;
  const _Float16* pA = A + (size_t)(bm + srow) * K + scol;
  const _Float16* pB = Bt + (size_t)(bn + srow) * K + scol;
  _Float16* lA = As + t * 8;
  _Float16* lB = Bs + t * 8;
  const size_t rowK64 = (size_t)64 * K;

#define STA(H, KT, BUF)                                                   \
  { const size_t _g = (size_t)((H) * 128) * K + (size_t)(KT) * 64;        \
    gload16(pA + _g, lA + (BUF) * 16384 + (H) * 8192);                    \
    gload16(pA + _g + rowK64, lA + (BUF) * 16384 + (H) * 8192 + 4096); }
#define STB(H, KT, BUF)                                                   \
  { const size_t _g = (size_t)((H) * 128) * K + (size_t)(KT) * 64;        \
    gload16(pB + _g, lB + (BUF) * 16384 + (H) * 8192);                    \
    gload16(pB + _g + rowK64, lB + (BUF) * 16384 + (H) * 8192 + 4096); }

  const int sw0 = (lr4 ^ (rl & 7)) << 3;
  const int sw1 = ((4 + lr4) ^ (rl & 7)) << 3;
  const int aoff = (wm * 64 + rl) * 64;
  const int boff = (wn * 32 + rl) * 64;

  f16x8 a_[4][2], b0_[2][2], b1_[2][2];
  f32x4 acc[2][2][4][2];  // [qm][qn][mf][nf]
#pragma unroll
  for (int qm = 0; qm < 2; ++qm)
#pragma unroll
    for (int qn = 0; qn < 2; ++qn)
#pragma unroll
      for (int mf = 0; mf < 4; ++mf)
#pragma unroll
        for (int nf = 0; nf < 2; ++nf) acc[qm][qn][mf][nf] = (f32x4)0.0f;

#define LOAD_A(QM, BUF)                                                 \
  { const _Float16* _p = As + (BUF) * 16384 + (QM) * 8192 + aoff;       \
    _Pragma("unroll") for (int mf = 0; mf < 4; ++mf) {                  \
      a_[mf][0] = *(const f16x8*)&_p[mf * 1024 + sw0];                  \
      a_[mf][1] = *(const f16x8*)&_p[mf * 1024 + sw1]; } }
#define LOAD_B(DST, QN, BUF)                                            \
  { const _Float16* _p = Bs + (BUF) * 16384 + (QN) * 8192 + boff;       \
    _Pragma("unroll") for (int nf = 0; nf < 2; ++nf) {                  \
      DST[nf][0] = *(const f16x8*)&_p[nf * 1024 + sw0];                 \
      DST[nf][1] = *(const f16x8*)&_p[nf * 1024 + sw1]; } }
#define MFMA_Q(QM, QN, BREG)                                            \
  __builtin_amdgcn_s_setprio(1);                                        \
  _Pragma("unroll") for (int mf = 0; mf < 4; ++mf)                      \
    _Pragma("unroll") for (int nf = 0; nf < 2; ++nf) {                  \
      acc[QM][QN][mf][nf] = __builtin_amdgcn_mfma_f32_16x16x32_f16(     \
          a_[mf][0], BREG[nf][0], acc[QM][QN][mf][nf], 0, 0, 0);        \
      acc[QM][QN][mf][nf] = __builtin_amdgcn_mfma_f32_16x16x32_f16(     \
          a_[mf][1], BREG[nf][1], acc[QM][QN][mf][nf], 0, 0, 0); }      \
  __builtin_amdgcn_s_setprio(0);
#define BAR()                                                           \
  do { __builtin_amdgcn_sched_barrier(0); __builtin_amdgcn_s_barrier(); \
       __builtin_amdgcn_sched_barrier(0); } while (0)
#define LGKM0()                                                         \
  do { asm volatile("s_waitcnt lgkmcnt(0)" ::: "memory");               \
       __builtin_amdgcn_sched_barrier(0); } while (0)

  // prologue: stage stream S[0..6] = A0,B0,A1,B1(kt0), A0,B0,A1(kt1)
  STA(0, 0, 0); STB(0, 0, 0); STA(1, 0, 0); STB(1, 0, 0);
  STA(0, 1, 1); STB(0, 1, 1); STA(1, 1, 1);
  asm volatile("s_waitcnt vmcnt(6)" ::: "memory");  // kt0's 8 loads landed
  BAR();
  LOAD_B(b0_, 0, 0);  // preload first quadrant's B (waited at ph0's LGKM0)

  for (int i = 0; i < (NKT >> 1) - 1; ++i) {
    const int k1 = 2 * i + 1, k2 = 2 * i + 2, k3 = 2 * i + 3;
    // ph0: quad(0,0) buf0 — reads A-h0 (b0_ preloaded); stage B1(k1)
    LOAD_A(0, 0); STB(1, k1, 1);
    BAR(); LGKM0(); MFMA_Q(0, 0, b0_); BAR();
    // ph1: quad(0,1) buf0 — reads B-h1; stage A0(k2)
    LOAD_B(b1_, 1, 0); STA(0, k2, 0);
    BAR(); LGKM0(); MFMA_Q(0, 1, b1_); BAR();
    // ph2: quad(1,0) buf0 — reads A-h1; stage B0(k2)
    LOAD_A(1, 0); STB(0, k2, 0);
    BAR(); LGKM0(); MFMA_Q(1, 0, b0_); BAR();
    // ph3: quad(1,1) buf0 — stage A1(k2); vmcnt(6) => kt1 fully landed;
    //      post-barrier preload b0_ of buf1 overlaps the MFMA cluster
    STA(1, k2, 0);
    asm volatile("s_waitcnt vmcnt(6)" ::: "memory");
    BAR();
    MFMA_Q(1, 1, b1_);
    LOAD_B(b0_, 0, 1);
    BAR();
    // ph4: quad(0,0) buf1 — reads A-h0; stage B1(k2)
    LOAD_A(0, 1); STB(1, k2, 0);
    BAR(); LGKM0(); MFMA_Q(0, 0, b0_); BAR();
    // ph5: quad(0,1) buf1 — reads B-h1; stage A0(k3)
    LOAD_B(b1_, 1, 1); STA(0, k3, 1);
    BAR(); LGKM0(); MFMA_Q(0, 1, b1_); BAR();
    // ph6: quad(1,0) buf1 — reads A-h1; stage B0(k3)
    LOAD_A(1, 1); STB(0, k3, 1);
    BAR(); LGKM0(); MFMA_Q(1, 0, b0_); BAR();
    // ph7: quad(1,1) buf1 — stage A1(k3); vmcnt(6) => kt2 fully landed;
    //      preload b0_ of buf0 (kt2 data) for next iter's ph0
    STA(1, k3, 1);
    asm volatile("s_waitcnt vmcnt(6)" ::: "memory");
    BAR();
    MFMA_Q(1, 1, b1_);
    LOAD_B(b0_, 0, 0);
    BAR();
  }
  // peeled last iter (kt = NKT-2 in buf0, NKT-1 in buf1): drain tail
  {
    const int k1 = NKT - 1;
    LOAD_A(0, 0); STB(1, k1, 1);
    BAR(); LGKM0(); MFMA_Q(0, 0, b0_); BAR();
    LOAD_B(b1_, 1, 0);
    BAR(); LGKM0(); MFMA_Q(0, 1, b1_); BAR();
    LOAD_A(1, 0);
    BAR(); LGKM0(); MFMA_Q(1, 0, b0_); BAR();
    asm volatile("s_waitcnt vmcnt(0)" ::: "memory");  // all stages landed
    BAR();
    MFMA_Q(1, 1, b1_);
    LOAD_B(b0_, 0, 1);
    BAR();
    LOAD_A(0, 1);
    BAR(); LGKM0(); MFMA_Q(0, 0, b0_); BAR();
    LOAD_B(b1_, 1, 1);
    BAR(); LGKM0(); MFMA_Q(0, 1, b1_); BAR();
    LOAD_A(1, 1);
    BAR(); LGKM0(); MFMA_Q(1, 0, b0_); BAR();
    MFMA_Q(1, 1, b1_);
  }

  // C write: row = bm + qm*128 + wm*64 + mf*16 + lr4*4 + ri; col = bn + qn*128 + wn*32 + nf*16 + rl
#pragma unroll
  for (int qm = 0; qm < 2; ++qm)
#pragma unroll
    for (int qn = 0; qn < 2; ++qn)
#pragma unroll
      for (int mf = 0; mf < 4; ++mf)
#pragma unroll
        for (int nf = 0; nf < 2; ++nf) {
          const int col = bn + qn * 128 + wn * 32 + nf * 16 + rl;
#pragma unroll
          for (int ri = 0; ri < 4; ++ri) {
            const int row = bm + qm * 128 + wm * 64 + mf * 16 + lr4 * 4 + ri;
            if (OUTF32)
              ((float*)Cout)[(size_t)row * N + col] = acc[qm][qn][mf][nf][ri];
            else
              ((_Float16*)Cout)[(size_t)row * N + col] = (_Float16)acc[qm][qn][mf][nf][ri];
          }
        }
#undef STA
#undef STB
#undef LOAD_A
#undef LOAD_B
#undef MFMA_Q
#undef BAR
#undef LGKM0
}

// ---------------- GEMM v3: m97-faithful 2-phase (kept for O-proj) ------------
template <bool OUTF32>
__global__ __launch_bounds__(256) void gemm3_kernel(const _Float16* __restrict__ A,
                                                    const _Float16* __restrict__ Bt,
                                                    void* __restrict__ Cout,
                                                    int M, int N, int K) {
  __shared__ __align__(16) _Float16 As[128 * 64];
  __shared__ __align__(16) _Float16 Bs[128 * 64];
  const int nwg = gridDim.x * gridDim.y;
  const int orig = blockIdx.y * gridDim.x + blockIdx.x;
  const int id = (orig & 7) * (nwg >> 3) + (orig >> 3);
  const int bx = id % gridDim.x, by = id / gridDim.x;
  const int bm = by * 128, bn = bx * 128;
  const int t = threadIdx.x, lane = t & 63;
  const int w = t >> 6, wm = w >> 1, wn = w & 1;
  const int rl = lane & 15, lr4 = lane >> 4;

  f32x4 acc[4][4];
#pragma unroll
  for (int i = 0; i < 4; ++i)
#pragma unroll
    for (int j = 0; j < 4; ++j) acc[i][j] = (f32x4)0.0f;

  for (int kt = 0; kt < K; kt += 64) {
#pragma unroll
    for (int i = 0; i < 4; ++i) {
      const int c = i * 256 + t;
      const int row = c >> 3, u = c & 7;
      gload16(&A[(size_t)(bm + row) * K + kt + ((u ^ (row & 7)) << 3)], &As[c * 8]);
    }
#pragma unroll
    for (int i = 0; i < 4; ++i) {
      const int c = i * 256 + t;
      const int row = c >> 3, u = c & 7;
      gload16(&Bt[(size_t)(bn + row) * K + kt + ((u ^ (row & 7)) << 3)], &Bs[c * 8]);
    }
    __syncthreads();
#pragma unroll
    for (int kk = 0; kk < 2; ++kk) {
      f16x8 af[4], bf[4];
#pragma unroll
      for (int i = 0; i < 4; ++i) {
        const int row = wm * 64 + i * 16 + rl;
        af[i] = *(const f16x8*)&As[row * 64 + (((kk * 4 + lr4) ^ (row & 7)) << 3)];
      }
#pragma unroll
      for (int j = 0; j < 4; ++j) {
        const int row = wn * 64 + j * 16 + rl;
        bf[j] = *(const f16x8*)&Bs[row * 64 + (((kk * 4 + lr4) ^ (row & 7)) << 3)];
      }
#pragma unroll
      for (int i = 0; i < 4; ++i)
#pragma unroll
        for (int j = 0; j < 4; ++j)
          acc[i][j] = __builtin_amdgcn_mfma_f32_16x16x32_f16(af[i], bf[j], acc[i][j], 0, 0, 0);
    }
    __syncthreads();
  }
#pragma unroll
  for (int i = 0; i < 4; ++i)
#pragma unroll
    for (int j = 0; j < 4; ++j) {
      const int col = bn + wn * 64 + j * 16 + rl;
#pragma unroll
      for (int ri = 0; ri < 4; ++ri) {
        const int row = bm + wm * 64 + i * 16 + lr4 * 4 + ri;
        if (OUTF32)
          ((float*)Cout)[(size_t)row * N + col] = acc[i][j][ri];
        else
          ((_Float16*)Cout)[(size_t)row * N + col] = (_Float16)acc[i][j][ri];
      }
    }
}

// ---------------- RoPE on Q,K (from QKV gemm out), scale folded into Q -------
__global__ __launch_bounds__(256) void rope_qk_kernel(const _Float16* __restrict__ QKVo,
                                                      const int* __restrict__ pos_ids,
                                                      const float* __restrict__ ct,
                                                      const float* __restrict__ st,
                                                      _Float16* __restrict__ Q,
                                                      _Float16* __restrict__ K) {
  int id = blockIdx.x * 256 + threadIdx.x;  // 2^22 = B*S*H*64
  int f = id & 63;
  int h = (id >> 6) & 15;
  int s_ = (id >> 10) & 2047;
  int b = (id >> 21) & 1;
  int row = b * SEQ + s_;
  int pos = pos_ids[row];
  float c = ct[pos * 64 + f], sn = st[pos * 64 + f];
  size_t base = (size_t)row * NQKV;
  float q1 = (float)QKVo[base + h * 128 + f];
  float q2 = (float)QKVo[base + h * 128 + f + 64];
  float k1 = (float)QKVo[base + 2048 + h * 128 + f];
  float k2 = (float)QKVo[base + 2048 + h * 128 + f + 64];
  const float scale = 0.08838834764831845f;  // 1/sqrt(128)
  size_t obase = (((size_t)(b * 16 + h)) * SEQ + s_) * 128;
  Q[obase + f]      = (_Float16)((q1 * c - q2 * sn) * scale);
  Q[obase + f + 64] = (_Float16)((q2 * c + q1 * sn) * scale);
  K[obase + f]      = (_Float16)(k1 * c - k2 * sn);
  K[obase + f + 64] = (_Float16)(k2 * c + k1 * sn);
}

// ---------------- V transpose: QKVo v-part -> Vt[bh][128][S] -----------------
__global__ __launch_bounds__(256) void v_transpose_kernel(const _Float16* __restrict__ QKVo,
                                                          _Float16* __restrict__ Vt) {
  __shared__ _Float16 tile[32][40];
  const int s0 = blockIdx.x * 32, d0 = blockIdx.y * 32, bh = blockIdx.z;
  const int b = bh >> 4, h = bh & 15;
  const int tx = threadIdx.x & 31, ty = threadIdx.x >> 5;
#pragma unroll
  for (int i = 0; i < 32; i += 8) {
    int s_ = s0 + ty + i;
    tile[ty + i][tx] = QKVo[(size_t)(b * SEQ + s_) * NQKV + 4096 + h * 128 + d0 + tx];
  }
  __syncthreads();
#pragma unroll
  for (int i = 0; i < 32; i += 8) {
    int d = d0 + ty + i;
    Vt[((size_t)bh * 128 + d) * SEQ + s0 + tx] = tile[tx][ty + i];
  }
}

// ---------------- flash attention, causal, pair-balanced ---------------------
__global__ __launch_bounds__(512) void attn_kernel(const _Float16* __restrict__ Q,
                                                   const _Float16* __restrict__ K,
                                                   const _Float16* __restrict__ Vt,
                                                   _Float16* __restrict__ O) {
  __shared__ __align__(16) _Float16 Ks[2][64 * 128];   // [key][dim], swizzled
  __shared__ __align__(16) _Float16 Vs[2][128 * 64];   // [dim][key], swizzled
  __shared__ __align__(16) _Float16 Ps[8][16 * 72];    // per-wave P round-trip
  const int bh = blockIdx.x;    // 0..31; bh%8 -> XCD: one head's K/V stays in one L2
  const int pair = blockIdx.y;  // 0..7
  const int b = bh >> 4, h = bh & 15;
  const int t = threadIdx.x, lane = t & 63, w = t >> 6;
  const int lr = lane >> 4, lc = lane & 15;
  const _Float16* Qb = Q + (size_t)bh * SEQ * 128;
  const _Float16* Kb = K + (size_t)bh * SEQ * 128;
  const _Float16* Vb = Vt + (size_t)bh * 128 * SEQ;

  auto stage = [&](int buf, int kb) {
    const int k0 = kb * 64;
#pragma unroll
    for (int i = 0; i < 2; ++i) {
      const int c = i * 512 + t;
      const int row = c >> 4, u = c & 15;
      gload16(&Kb[(size_t)(k0 + row) * 128 + ((u ^ (row & 7)) * 8)], &Ks[buf][c * 8]);
    }
#pragma unroll
    for (int i = 0; i < 2; ++i) {
      const int c = i * 512 + t;
      const int dim = c >> 3, u = c & 7;
      gload16(&Vb[(size_t)dim * SEQ + k0 + ((u ^ (dim & 7)) * 8)], &Vs[buf][c * 8]);
    }
  };

  for (int half = 0; half < 2; ++half) {
    const int j = half ? (15 - pair) : pair;
    const int q0 = j * 128;
    const int nkb = 2 * j + 2;
    const int rowmin = q0 + w * 16;

    f16x8 qf[4];
    {
      const int qrow = q0 + w * 16 + lc;
#pragma unroll
      for (int kk = 0; kk < 4; ++kk)
        qf[kk] = *(const f16x8*)&Qb[(size_t)qrow * 128 + kk * 32 + lr * 8];
    }
    f32x4 acco[8];
#pragma unroll
    for (int i = 0; i < 8; ++i) acco[i] = (f32x4)0.0f;
    float m_r[4] = {-1e30f, -1e30f, -1e30f, -1e30f};
    float l_r[4] = {0.f, 0.f, 0.f, 0.f};

    stage(0, 0);
    __syncthreads();
    for (int kb = 0; kb < nkb; ++kb) {
      const int cur = kb & 1;
      if (kb + 1 < nkb) stage(cur ^ 1, kb + 1);
      const int k0 = kb * 64;
      if (k0 <= rowmin + 15) {
        f32x4 sacc[4];
#pragma unroll
        for (int jj = 0; jj < 4; ++jj) sacc[jj] = (f32x4)0.0f;
#pragma unroll
        for (int jj = 0; jj < 4; ++jj) {
          const int krow = jj * 16 + lc;
#pragma unroll
          for (int kk = 0; kk < 4; ++kk) {
            const int idx = (krow * 128 + kk * 32 + lr * 8) ^ ((krow & 7) << 3);
            f16x8 kf = *(const f16x8*)&Ks[cur][idx];
            sacc[jj] = __builtin_amdgcn_mfma_f32_16x16x32_f16(qf[kk], kf, sacc[jj], 0, 0, 0);
          }
        }
        const bool diag = (k0 + 63 > rowmin);
#pragma unroll
        for (int r = 0; r < 4; ++r) {
          const int rowi = rowmin + lr * 4 + r;
          float s[4], mx = -1e30f;
#pragma unroll
          for (int jj = 0; jj < 4; ++jj) {
            float sv = sacc[jj][r];
            if (diag && (k0 + jj * 16 + lc > rowi)) sv = -1e30f;
            s[jj] = sv;
            mx = fmaxf(mx, sv);
          }
#pragma unroll
          for (int msk = 1; msk < 16; msk <<= 1) mx = fmaxf(mx, __shfl_xor(mx, msk));
          const float mn = fmaxf(m_r[r], mx);
          const float sc = __expf(m_r[r] - mn);
          float rs = 0.f;
#pragma unroll
          for (int jj = 0; jj < 4; ++jj) {
            float pv = __expf(s[jj] - mn);
            rs += pv;
            Ps[w][(lr * 4 + r) * 72 + jj * 16 + lc] = (_Float16)pv;
          }
#pragma unroll
          for (int msk = 1; msk < 16; msk <<= 1) rs += __shfl_xor(rs, msk);
          l_r[r] = l_r[r] * sc + rs;
          m_r[r] = mn;
#pragma unroll
          for (int tt = 0; tt < 8; ++tt) acco[tt][r] *= sc;
        }
#pragma unroll
        for (int tt = 0; tt < 8; ++tt) {
          const int dim = tt * 16 + lc;
#pragma unroll
          for (int ch = 0; ch < 2; ++ch) {
            f16x8 pf = *(const f16x8*)&Ps[w][lc * 72 + ch * 32 + lr * 8];
            const int vidx = (dim * 64 + ch * 32 + lr * 8) ^ ((dim & 7) << 3);
            f16x8 vf = *(const f16x8*)&Vs[cur][vidx];
            acco[tt] = __builtin_amdgcn_mfma_f32_16x16x32_f16(pf, vf, acco[tt], 0, 0, 0);
          }
        }
      }
      __syncthreads();
    }
#pragma unroll
    for (int tt = 0; tt < 8; ++tt) {
      const int col = h * 128 + tt * 16 + lc;
#pragma unroll
      for (int r = 0; r < 4; ++r) {
        const int row = q0 + w * 16 + lr * 4 + r;
        O[(size_t)(b * SEQ + row) * DM + col] = (_Float16)(acco[tt][r] / l_r[r]);
      }
    }
  }
}

// ---------------- launch ------------------------------------------------------
extern "C" void kernel_launch(void* const* d_in, const int* in_sizes, int n_in,
                              void* d_out, int out_size, void* d_ws, size_t ws_size,
                              hipStream_t stream) {
  const float* hidden = (const float*)d_in[0];
  // d_in[1]: attention_mask — exactly the causal mask; applied analytically.
  const int* pos_ids = (const int*)d_in[2];
  const float* Wq = (const float*)d_in[3];
  const float* Wk = (const float*)d_in[4];
  const float* Wv = (const float*)d_in[5];
  const float* Wo = (const float*)d_in[6];

  char* ws = (char*)d_ws;
  _Float16* Xb    = (_Float16*)(ws + 0);
  _Float16* Wqkvt = (_Float16*)(ws + 16777216);
  _Float16* Wot   = (_Float16*)(ws + 41943040);
  _Float16* QKVo  = (_Float16*)(ws + 50331648);
  _Float16* Kbuf  = (_Float16*)(ws + 100663296);
  float* ct       = (float*)(ws + 117440512);
  float* st       = (float*)(ws + 117964800);
  _Float16* Vtbuf = Xb;     // alias (Xb dead after QKV gemm)
  _Float16* Qbuf  = Wqkvt;  // alias (Wqkv_t dead after QKV gemm)
  _Float16* Obuf  = QKVo;   // alias (QKVo dead after rope + v-transpose)

  cvt_x_kernel<<<8192, 256, 0, stream>>>(hidden, Xb, 2097152);
  wtrans_all_kernel<<<dim3(64, 64, 4), 256, 0, stream>>>(Wq, Wk, Wv, Wo, Wqkvt, Wot);
  rope_table_kernel<<<512, 256, 0, stream>>>(ct, st);

  // QKV: M=4096, N=6144 -> grid 24x16 = 384 blocks, 256^2 8-phase
  gemm8_kernel<false><<<dim3(24, 16), 512, 0, stream>>>(Xb, Wqkvt, QKVo, 4096, 6144, 2048);

  rope_qk_kernel<<<16384, 256, 0, stream>>>(QKVo, pos_ids, ct, st, Qbuf, Kbuf);
  v_transpose_kernel<<<dim3(64, 4, 32), 256, 0, stream>>>(QKVo, Vtbuf);

  attn_kernel<<<dim3(32, 8), 512, 0, stream>>>(Qbuf, Kbuf, Vtbuf, Obuf);

  // O-proj: M=4096, N=2048 -> grid 16x32 = 512 blocks (balanced, m97 structure)
  gemm3_kernel<true><<<dim3(16, 32), 256, 0, stream>>>(Obuf, Wot, d_out, 4096, 2048, 2048);
}